// Round 5
// baseline (1994.648 us; speedup 1.0000x reference)
//
#include <hip/hip_runtime.h>
#include <hip/hip_bf16.h>

typedef __attribute__((ext_vector_type(8))) short short8;
typedef __attribute__((ext_vector_type(4))) float floatx4;

#define F2BF __float2bfloat16
#define BF2F __bfloat162float

// ---------------- workspace layout (byte offsets), total ~142.1 MiB ----------------
#define WS_A      0UL                // bf16 A [8192][512]  (img^T + pe)
#define WS_SRCN   8388608UL          // f32 srcN [8][1024][512] (NHWC src)
#define WS_WTB    25165824UL         // bf16 W_t cast [512][512]
#define WS_WR1    25690112UL         // bf16 conv1 w repacked [9][512][512]
#define WS_WR2    30408704UL         // bf16 conv2 w repacked [9][256][512]
#define WS_SRCB   32768000UL         // bf16 src NHWC [8192][512]
#define WS_Y1     41156608UL         // bf16 y1/x1 [8][64][64][512]
#define WS_Y2     74711040UL         // bf16 y2/x2 [8][128][128][256]
#define WS_STATS  141819904UL        // f32 [4][512]
#define WS_ANS    141828096UL        // f32 [8][512]
#define WS_ANSV   141844480UL        // f32 [8][512]
#define WS_QA     141860864UL        // f32 [8][1024]
#define WS_WORD   141893632UL        // f32 [8][512]
#define WS_WORD2  141910016UL        // f32 [8][2305]
#define WS_EFFW   141983776UL        // f32 [8][9][256]
#define WS_EFFB   142057504UL        // f32 [8][9]
#define WS_FLAG   142057792UL        // int dtype flag (1 = inputs/outputs bf16)

// d_out element offsets: masks [0,131072) ; logits [131072,131256) ; src [131256, 4325560)
#define OUT_LOGITS 131072
#define OUT_SRC    131256

// ---- dual-dtype input read / output write (flag picked at runtime) ----
__device__ __forceinline__ float inp(const void* p, long i, int isbf) {
    return isbf ? BF2F(((const __hip_bfloat16*)p)[i]) : ((const float*)p)[i];
}
__device__ __forceinline__ void outw(void* p, long i, float v, int isbf) {
    if (isbf) ((__hip_bfloat16*)p)[i] = F2BF(v);
    else      ((float*)p)[i] = v;
}
__device__ __forceinline__ float bfbits2f(short s) {
    unsigned int u = ((unsigned int)(unsigned short)s) << 16;
    float f; __builtin_memcpy(&f, &u, 4); return f;
}
__device__ __forceinline__ short f2bfbits(float f) {
    __hip_bfloat16 h = F2BF(f);
    short s; __builtin_memcpy(&s, &h, 2); return s;
}

// ---- dtype detector (validated round 3) ----
__global__ void k_detect(const void* img, int* flag) {
    __shared__ int cnt[256];
    int tid = threadIdx.x;
    const unsigned short* u = (const unsigned short*)img;
    int c = 0;
    for (int i = tid * 2; i < 8192; i += 512) {
        int e = (u[i] >> 7) & 0xFF;
        if (e >= 100 && e <= 150) ++c;
    }
    cnt[tid] = c;
    __syncthreads();
    for (int s = 128; s > 0; s >>= 1) { if (tid < s) cnt[tid] += cnt[tid + s]; __syncthreads(); }
    if (tid == 0) *flag = (cnt[0] > 2458) ? 1 : 0;
}

__device__ __forceinline__ float pe_val(int n, int c) {
    float pos = (c < 256) ? (float)(n & 31) : (float)(n >> 5);
    int i = ((c < 256) ? c : (c - 256)) >> 1;
    float ang = pos * expf(-0.0719557841560639f * (float)i);
    return (c & 1) ? cosf(ang) : sinf(ang);
}

// ---- build A[b*1024+n][c] = img[b][c][n] + pe(n,c), bf16, via LDS transpose ----
__global__ void k_buildA(const void* __restrict__ img, __hip_bfloat16* __restrict__ A,
                         const int* __restrict__ dfl) {
    int isbf = *dfl;
    int bid = blockIdx.x;
    int nt = bid & 31, ct = (bid >> 5) & 15, b = bid >> 9;
    __shared__ float T[32][33];
    int tx = threadIdx.x, ty = threadIdx.y;
    int c0 = ct * 32, n0 = nt * 32;
    for (int j = 0; j < 4; ++j) {
        int c = c0 + ty + j * 8;
        T[ty + j * 8][tx] = inp(img, ((long)(b * 512 + c)) * 1024 + n0 + tx, isbf);
    }
    __syncthreads();
    for (int j = 0; j < 4; ++j) {
        int n = n0 + ty + j * 8;
        int c = c0 + tx;
        float v = T[tx][ty + j * 8] + pe_val(n, c);
        A[((long)(b * 1024 + n)) * 512 + c] = F2BF(v);
    }
}

// ---- fused weight prep: blocks [0,1024) WR1 repack, [1024,1536) WR2 repack,
//      [1536,1792) cast Wt->WTB ----
__global__ void k_prep(const void* __restrict__ cw1, const void* __restrict__ cw2,
                       const void* __restrict__ Wt, __hip_bfloat16* __restrict__ WR1,
                       __hip_bfloat16* __restrict__ WR2, __hip_bfloat16* __restrict__ WTB,
                       const int* __restrict__ dfl) {
    int isbf = *dfl;
    int bid = blockIdx.x;
    int tid = threadIdx.x;
    if (bid < 1536) {
        const void* w; __hip_bfloat16* wR; int total_r, r0;
        if (bid < 1024) { w = cw1; wR = WR1; total_r = 512 * 512; r0 = bid * 256; }
        else            { w = cw2; wR = WR2; total_r = 256 * 512; r0 = (bid - 1024) * 256; }
        __shared__ float W[2304];
        for (int e = tid; e < 2304; e += 256) W[e] = inp(w, (long)r0 * 9 + e, isbf);
        __syncthreads();
#pragma unroll
        for (int tap = 0; tap < 9; ++tap)
            wR[(long)tap * total_r + r0 + tid] = F2BF(W[tid * 9 + tap]);
    } else {
        for (int i = (bid - 1536) * 256 + tid; i < 512 * 512; i += 256 * 256)
            WTB[i] = F2BF(inp(Wt, i, isbf));
    }
}

// ---- MFMA GEMM: srcN/srcB[m][n] = sum_k A[m][k]*Wt[n][k], M=8192 N=512 K=512 ----
__global__ __launch_bounds__(256) void k_gemm1(const __hip_bfloat16* __restrict__ A,
                                               const __hip_bfloat16* __restrict__ Bw,
                                               float* __restrict__ srcN,
                                               __hip_bfloat16* __restrict__ srcB) {
    __shared__ __align__(16) __hip_bfloat16 As[128 * 32];
    __shared__ __align__(16) __hip_bfloat16 Bs[128 * 32];
    int m0 = blockIdx.x * 128, n0 = blockIdx.y * 128;
    int tid = threadIdx.x;
    int wave = tid >> 6, l = tid & 63, lm = l & 15, q = l >> 4;
    int wm = wave & 1, wn = wave >> 1;
    floatx4 zero4 = {0.f, 0.f, 0.f, 0.f};
    floatx4 acc[4][4];
    for (int i = 0; i < 4; ++i) for (int j = 0; j < 4; ++j) acc[i][j] = zero4;
    for (int k0 = 0; k0 < 512; k0 += 32) {
        __syncthreads();
        for (int s = tid; s < 512; s += 256) {
            int m = s >> 2, qq = s & 3;
            *(short8*)(As + m * 32 + qq * 8) = *(const short8*)(A + ((long)(m0 + m)) * 512 + k0 + qq * 8);
            *(short8*)(Bs + m * 32 + qq * 8) = *(const short8*)(Bw + ((long)(n0 + m)) * 512 + k0 + qq * 8);
        }
        __syncthreads();
        short8 af[4], bfv[4];
#pragma unroll
        for (int t = 0; t < 4; ++t) af[t] = *(short8*)(As + (wm * 64 + t * 16 + lm) * 32 + q * 8);
#pragma unroll
        for (int t = 0; t < 4; ++t) bfv[t] = *(short8*)(Bs + (wn * 64 + t * 16 + lm) * 32 + q * 8);
#pragma unroll
        for (int i = 0; i < 4; ++i)
#pragma unroll
            for (int j = 0; j < 4; ++j)
                acc[i][j] = __builtin_amdgcn_mfma_f32_16x16x32_bf16(af[i], bfv[j], acc[i][j], 0, 0, 0);
    }
#pragma unroll
    for (int i = 0; i < 4; ++i)
#pragma unroll
        for (int j = 0; j < 4; ++j)
#pragma unroll
            for (int r = 0; r < 4; ++r) {
                int m = m0 + wm * 64 + i * 16 + q * 4 + r;
                int n = n0 + wn * 64 + j * 16 + lm;
                float v = acc[i][j][r];
                srcN[((long)m) * 512 + n] = v;
                srcB[((long)m) * 512 + n] = F2BF(v);
            }
}

// ---- src output: d_out src region (NCHW) = transpose of srcN ----
__global__ void k_src_out(const float* __restrict__ srcN, void* __restrict__ dst,
                          const int* __restrict__ dfl) {
    int isbf = *dfl;
    int bid = blockIdx.x;
    int nt = bid & 31, dt = (bid >> 5) & 15, b = bid >> 9;
    __shared__ float T[32][33];
    int tx = threadIdx.x, ty = threadIdx.y;
    int n0 = nt * 32, d0 = dt * 32;
    for (int j = 0; j < 4; ++j)
        T[ty + j * 8][tx] = srcN[((long)(b * 1024 + n0 + ty + j * 8)) * 512 + d0 + tx];
    __syncthreads();
    for (int j = 0; j < 4; ++j)
        outw(dst, (long)OUT_SRC + ((long)(b * 512 + d0 + ty + j * 8)) * 1024 + n0 + tx,
             T[tx][ty + j * 8], isbf);
}

// ---- ans[b][d] = mean_n srcN[b][n][d] ----
__global__ void k_ans(const float* __restrict__ srcN, float* __restrict__ ans) {
    int bid = blockIdx.x;
    int b = bid >> 3, dt = bid & 7;
    int tid = threadIdx.x;
    int l = tid & 63, sl = tid >> 6;
    int d = dt * 64 + l;
    float a = 0.f;
    for (int n = sl; n < 1024; n += 4) a += srcN[((long)(b * 1024 + n)) * 512 + d];
    __shared__ float red[4][65];
    red[sl][l] = a;
    __syncthreads();
    if (sl == 0) ans[b * 512 + d] = (red[0][l] + red[1][l] + red[2][l] + red[3][l]) * (1.f / 1024.f);
}

// ---- fused: ans_vec = ans@lnW^T + lnb ; qa = [state, ans_vec] ; word = softmax-mul ----
__global__ void k_answord(const float* __restrict__ ans, const void* __restrict__ lw,
                          const void* __restrict__ lb, const void* __restrict__ state,
                          float* __restrict__ ansv, float* __restrict__ qa,
                          float* __restrict__ word, const int* __restrict__ dfl) {
    int isbf = *dfl;
    int b = blockIdx.x, tid = threadIdx.x;
    __shared__ float aL[512];
    __shared__ float L[1024];
    __shared__ float red[256];
    aL[tid] = ans[b * 512 + tid];
    aL[tid + 256] = ans[b * 512 + tid + 256];
    __syncthreads();
    for (int d = tid; d < 512; d += 256) {
        float acc = inp(lb, d, isbf);
        for (int c = 0; c < 512; ++c) acc += aL[c] * inp(lw, (long)d * 512 + c, isbf);
        ansv[b * 512 + d] = acc;
        qa[b * 1024 + 512 + d] = acc;
        L[512 + d] = acc;
    }
    float s0 = inp(state, b * 512 + tid, isbf);
    float s1 = inp(state, b * 512 + tid + 256, isbf);
    qa[b * 1024 + tid] = s0;
    qa[b * 1024 + tid + 256] = s1;
    L[tid] = s0;
    L[tid + 256] = s1;
    __syncthreads();
    float m = fmaxf(fmaxf(L[tid], L[tid + 256]), fmaxf(L[tid + 512], L[tid + 768]));
    red[tid] = m; __syncthreads();
    for (int s = 128; s > 0; s >>= 1) { if (tid < s) red[tid] = fmaxf(red[tid], red[tid + s]); __syncthreads(); }
    float M = red[0]; __syncthreads();
    float z = expf(L[tid] - M) + expf(L[tid + 256] - M) + expf(L[tid + 512] - M) + expf(L[tid + 768] - M);
    red[tid] = z; __syncthreads();
    for (int s = 128; s > 0; s >>= 1) { if (tid < s) red[tid] += red[tid + s]; __syncthreads(); }
    float Z = red[0];
    for (int j = tid; j < 512; j += 256) {
        float o1 = expf(L[j] - M) / Z * L[j];
        float o2 = expf(L[j + 512] - M) / Z * L[j + 512];
        word[b * 512 + j] = o1 + o2;
    }
}

// ---- word2[b][n] = word@txt_w^T + txt_b ----
__global__ void k_txt(const float* __restrict__ word, const void* __restrict__ tw,
                      const void* __restrict__ tb, float* __restrict__ word2,
                      const int* __restrict__ dfl) {
    int isbf = *dfl;
    int n = blockIdx.x, tid = threadIdx.x;
    __shared__ float wL[8][512];
    __shared__ float red[256 * 8];
    for (int e = tid; e < 4096; e += 256) wL[e >> 9][e & 511] = word[e];
    __syncthreads();
    float acc[8] = {0, 0, 0, 0, 0, 0, 0, 0};
    for (int c = tid; c < 512; c += 256) {
        float tv = inp(tw, (long)n * 512 + c, isbf);
        for (int b = 0; b < 8; ++b) acc[b] += wL[b][c] * tv;
    }
    for (int b = 0; b < 8; ++b) red[tid * 8 + b] = acc[b];
    __syncthreads();
    for (int s = 128; s > 0; s >>= 1) {
        if (tid < s) for (int b = 0; b < 8; ++b) red[tid * 8 + b] += red[(tid + s) * 8 + b];
        __syncthreads();
    }
    if (tid < 8) word2[tid * 2305 + n] = red[tid] + inp(tb, n, isbf);
}

// ---- eff_w[b][tap][c2] = sum_cx dyn_w[b][cx][tap]*w3[cx][c2]; effb ----
__global__ void k_eff(const float* __restrict__ word2, const void* __restrict__ w3,
                      const void* __restrict__ b3, float* __restrict__ effw,
                      float* __restrict__ effb, const int* __restrict__ dfl) {
    int isbf = *dfl;
    int bid = blockIdx.x;
    int b = bid / 9, tap = bid - b * 9;
    int tid = threadIdx.x;
    __shared__ float dw[256];
    dw[tid] = word2[b * 2305 + tid * 9 + tap];
    __syncthreads();
    float acc = 0.f;
    for (int c = 0; c < 256; ++c) acc += dw[c] * inp(w3, c * 256 + tid, isbf);
    effw[(b * 9 + tap) * 256 + tid] = acc;
    if (tid == 0) {
        float e = 0.f;
        for (int c = 0; c < 256; ++c) e += dw[c] * inp(b3, c, isbf);
        effb[b * 9 + tap] = e;
    }
}

// ---- 3x3 pad1 conv on 2x-bilinear-upsampled NHWC bf16 input, Cin=512, bf16 MFMA ----
// 512-thread blocks (8 waves), acc[4][2] (32 AGPR/wave) -> <=128 regs/wave
// -> 4 waves/SIMD (2 blocks/CU). Same validated index math as round 4.
__global__ __launch_bounds__(512, 4) void k_conv_up3(const __hip_bfloat16* __restrict__ in,
                                                     const __hip_bfloat16* __restrict__ wRb,
                                                     __hip_bfloat16* __restrict__ out,
                                                     int inH, int inW, int Cout) {
    int OH = inH * 2, OW = inW * 2;
    int tXn = OW >> 4, tYn = OH >> 3;
    int bid = blockIdx.x;
    int tX = bid % tXn; int tmp = bid / tXn; int tY = tmp % tYn; int b = tmp / tYn;
    int co0 = blockIdx.y * 128;
    __shared__ __align__(16) __hip_bfloat16 Os[60 * 32];    // orig tile 6y x 10x
    __shared__ __align__(16) __hip_bfloat16 Ah[180 * 32];   // up halo 10y x 18x
    int tid = threadIdx.x;
    int wave = tid >> 6, l = tid & 63, lm = l & 15, q = l >> 4;
    int wm = wave & 1, wn = wave >> 1;   // wm: py band, wn: 0..3 co-32 group
    int R0m1 = (tY << 2) - 1;
    int C0m1 = (tX << 3) - 1;
    floatx4 zero4 = {0.f, 0.f, 0.f, 0.f};
    floatx4 acc[4][2];
    for (int i = 0; i < 4; ++i) for (int j = 0; j < 2; ++j) acc[i][j] = zero4;

    for (int ci0 = 0; ci0 < 512; ci0 += 32) {
        __syncthreads();
        // stage orig-res tile (clamped): 60 px x 32 ci = 240 short8 loads
        if (tid < 240) {
            int p = tid >> 2, sub = tid & 3;
            int r = p / 10, cx = p - r * 10;
            int gr = R0m1 + r; gr = gr < 0 ? 0 : (gr > inH - 1 ? inH - 1 : gr);
            int gc = C0m1 + cx; gc = gc < 0 ? 0 : (gc > inW - 1 ? inW - 1 : gc);
            *(short8*)(Os + p * 32 + sub * 8) =
                *(const short8*)(in + ((long)(b * inH + gr) * inW + gc) * 512 + ci0 + sub * 8);
        }
        __syncthreads();
        // build upsampled halo from LDS: 180 px x 4 channel-octets (validated lerp)
        for (int e = tid; e < 720; e += 512) {
            int p = e >> 2, sub = e & 3;
            int hy = p / 18, hx = p - hy * 18;
            int gy = (tY << 3) + hy - 1, gx = (tX << 4) + hx - 1;
            short8 res = {0, 0, 0, 0, 0, 0, 0, 0};
            if (gy >= 0 && gy < OH && gx >= 0 && gx < OW) {
                int r0; float wy0;
                if (gy & 1) { r0 = gy >> 1; wy0 = 0.75f; } else { r0 = (gy >> 1) - 1; wy0 = 0.25f; }
                int r1 = r0 + 1;
                if (r0 < 0) r0 = 0; if (r1 > inH - 1) r1 = inH - 1;
                int s0; float wx0;
                if (gx & 1) { s0 = gx >> 1; wx0 = 0.75f; } else { s0 = (gx >> 1) - 1; wx0 = 0.25f; }
                int s1 = s0 + 1;
                if (s0 < 0) s0 = 0; if (s1 > inW - 1) s1 = inW - 1;
                int lr0 = r0 - R0m1, lr1 = r1 - R0m1;
                int lc0 = s0 - C0m1, lc1 = s1 - C0m1;
                float wy1 = 1.f - wy0, wx1 = 1.f - wx0;
                float w00 = wy0 * wx0, w01 = wy0 * wx1, w10 = wy1 * wx0, w11 = wy1 * wx1;
                short8 v00 = *(const short8*)(Os + (lr0 * 10 + lc0) * 32 + sub * 8);
                short8 v01 = *(const short8*)(Os + (lr0 * 10 + lc1) * 32 + sub * 8);
                short8 v10 = *(const short8*)(Os + (lr1 * 10 + lc0) * 32 + sub * 8);
                short8 v11 = *(const short8*)(Os + (lr1 * 10 + lc1) * 32 + sub * 8);
#pragma unroll
                for (int k = 0; k < 8; ++k) {
                    float f = w00 * bfbits2f(v00[k]) + w01 * bfbits2f(v01[k]) +
                              w10 * bfbits2f(v10[k]) + w11 * bfbits2f(v11[k]);
                    res[k] = f2bfbits(f);
                }
            }
            *(short8*)(Ah + p * 32 + sub * 8) = res;
        }
        __syncthreads();
        // 9 taps: B frags direct from global (L2), A frags from LDS halo, no barriers
#pragma unroll
        for (int tap = 0; tap < 9; ++tap) {
            int ky = tap / 3, kx = tap - ky * 3;
            short8 bfv[2];
#pragma unroll
            for (int t = 0; t < 2; ++t)
                bfv[t] = *(const short8*)(wRb + ((long)(tap * Cout + co0 + wn * 32 + t * 16 + lm)) * 512 + ci0 + q * 8);
            short8 af[4];
#pragma unroll
            for (int t = 0; t < 4; ++t)
                af[t] = *(short8*)(Ah + ((wm * 4 + t + ky) * 18 + lm + kx) * 32 + q * 8);
#pragma unroll
            for (int i = 0; i < 4; ++i)
#pragma unroll
                for (int j = 0; j < 2; ++j)
                    acc[i][j] = __builtin_amdgcn_mfma_f32_16x16x32_bf16(af[i], bfv[j], acc[i][j], 0, 0, 0);
        }
    }
#pragma unroll
    for (int i = 0; i < 4; ++i) {
        int py = wm * 4 + i;
#pragma unroll
        for (int j = 0; j < 2; ++j) {
            int cob = co0 + wn * 32 + j * 16 + lm;
#pragma unroll
            for (int r = 0; r < 4; ++r) {
                int pxc = q * 4 + r;
                int oy = (tY << 3) + py, ox = (tX << 4) + pxc;
                out[(((long)(b * OH + oy)) * OW + ox) * Cout + cob] = F2BF(acc[i][j][r]);
            }
        }
    }
}

// ---- per-channel sum / sumsq (atomics into zeroed stats) ----
__global__ void k_stats(const __hip_bfloat16* __restrict__ y, float* __restrict__ s1,
                        float* __restrict__ s2, int C, int npix) {
    int gid = blockIdx.x * 256 + threadIdx.x;
    int c = gid & (C - 1);
    int sl = gid / C;
    int S = (gridDim.x * 256) / C;
    float a = 0.f, a2 = 0.f;
    for (int p = sl; p < npix; p += S) {
        float v = BF2F(y[(long)p * C + c]);
        a += v; a2 += v * v;
    }
    atomicAdd(s1 + c, a);
    atomicAdd(s2 + c, a2);
}

// ---- in-place batchnorm(batch stats)+relu on bf16 NHWC ----
__global__ void k_bn(__hip_bfloat16* __restrict__ y, const float* __restrict__ s1,
                     const float* __restrict__ s2, const void* __restrict__ g,
                     const void* __restrict__ bb, int C, long total, float invN,
                     const int* __restrict__ dfl) {
    int isbf = *dfl;
    long stride = (long)gridDim.x * 256;
    for (long i = blockIdx.x * 256L + threadIdx.x; i < total; i += stride) {
        int c = (int)(i & (C - 1));
        float m = s1[c] * invN;
        float var = s2[c] * invN - m * m;
        float sc = inp(g, c, isbf) * rsqrtf(var + 1e-5f);
        float sh = inp(bb, c, isbf) - m * sc;
        float v = BF2F(y[i]) * sc + sh;
        y[i] = F2BF(v > 0.f ? v : 0.f);
    }
}

// ---- masks: fused (conv3 ∘ dyn grouped conv) via eff_w; vectorized LDS reads ----
__global__ __launch_bounds__(256) void k_masks(const __hip_bfloat16* __restrict__ x2,
                                               const float* __restrict__ effw,
                                               const float* __restrict__ effb,
                                               const float* __restrict__ word2,
                                               void* __restrict__ mout,
                                               const int* __restrict__ dfl) {
    int isbf = *dfl;
    int bid = blockIdx.x;
    int tX = bid & 15, tY = (bid >> 4) & 15, b = bid >> 8;
    __shared__ __align__(16) __hip_bfloat16 H[100 * 264];   // stride 264: 528B, 16B-aligned
    __shared__ __align__(16) float EW[9 * 256];
    __shared__ float EB[9];
    __shared__ float red[4][64];
    int tid = threadIdx.x;
    for (int e = tid; e < 25600; e += 256) {
        int c = e & 255, p = e >> 8;
        int hy = p / 10, hx = p - hy * 10;
        int gy = tY * 8 + hy - 1, gx = tX * 8 + hx - 1;
        __hip_bfloat16 v = F2BF(0.f);
        if (gy >= 0 && gy < 128 && gx >= 0 && gx < 128)
            v = x2[(((long)(b * 128 + gy)) * 128 + gx) * 256 + c];
        H[p * 264 + c] = v;
    }
    for (int e = tid; e < 2304; e += 256) EW[e] = effw[b * 2304 + e];
    if (tid < 9) EB[tid] = effb[b * 9 + tid];
    __syncthreads();
    int px = tid & 63, part = tid >> 6;
    int py = px >> 3, pxc = px & 7;
    int cbase = part * 64;
    float acc = 0.f;
    for (int tap = 0; tap < 9; ++tap) {
        int ky = tap / 3, kx = tap - ky * 3;
        int hp = (py + ky) * 10 + pxc + kx;
        const __hip_bfloat16* hrow = H + (long)hp * 264 + cbase;
        const float* erow = EW + tap * 256 + cbase;
#pragma unroll
        for (int c8 = 0; c8 < 8; ++c8) {
            short8 h8 = *(const short8*)(hrow + c8 * 8);
            floatx4 e0 = *(const floatx4*)(erow + c8 * 8);
            floatx4 e1 = *(const floatx4*)(erow + c8 * 8 + 4);
            acc += bfbits2f(h8[0]) * e0[0] + bfbits2f(h8[1]) * e0[1] +
                   bfbits2f(h8[2]) * e0[2] + bfbits2f(h8[3]) * e0[3] +
                   bfbits2f(h8[4]) * e1[0] + bfbits2f(h8[5]) * e1[1] +
                   bfbits2f(h8[6]) * e1[2] + bfbits2f(h8[7]) * e1[3];
        }
    }
    red[part][px] = acc;
    __syncthreads();
    if (part == 0) {
        float s = red[0][px] + red[1][px] + red[2][px] + red[3][px];
        int oy = tY * 8 + py, ox = tX * 8 + pxc;
        float bias = word2[b * 2305 + 2304];
        for (int tap = 0; tap < 9; ++tap) {
            int ky = tap / 3, kx = tap - ky * 3;
            int iy = oy + ky - 1, ix = ox + kx - 1;
            if (iy >= 0 && iy < 128 && ix >= 0 && ix < 128) bias += EB[tap];
        }
        outw(mout, b * 16384 + oy * 128 + ox, s + bias, isbf);
    }
}

// ---- router/gates/experts -> logits ----
__global__ void k_router(const float* __restrict__ qa, const float* __restrict__ ansv,
                         const void* __restrict__ w1, const void* __restrict__ b1,
                         const void* __restrict__ w2, const void* __restrict__ b2,
                         const void* __restrict__ lw2, const void* __restrict__ lb2,
                         const void* __restrict__ ew, const void* __restrict__ ebias,
                         void* __restrict__ out, const int* __restrict__ dfl) {
    int isbf = *dfl;
    int b = blockIdx.x, tid = threadIdx.x;
    __shared__ float qL[1024], hid[256], gates[8], feat[128], avL[512];
    for (int j = tid; j < 1024; j += 256) qL[j] = qa[b * 1024 + j];
    for (int j = tid; j < 512; j += 256) avL[j] = ansv[b * 512 + j];
    __syncthreads();
    float h = inp(b1, tid, isbf);
    for (int k = 0; k < 1024; ++k) h += qL[k] * inp(w1, (long)tid * 1024 + k, isbf);
    hid[tid] = h > 0.f ? h : 0.f;
    __syncthreads();
    if (tid < 8) {
        float gl = inp(b2, tid, isbf);
        for (int j = 0; j < 256; ++j) gl += hid[j] * inp(w2, tid * 256 + j, isbf);
        gates[tid] = gl;
    }
    __syncthreads();
    if (tid == 0) {
        float mx = gates[0];
        for (int e = 1; e < 8; ++e) mx = fmaxf(mx, gates[e]);
        float z = 0.f;
        for (int e = 0; e < 8; ++e) { gates[e] = expf(gates[e] - mx); z += gates[e]; }
        for (int e = 0; e < 8; ++e) gates[e] /= z;
    }
    if (tid < 128) {
        float f = inp(lb2, tid, isbf);
        for (int c = 0; c < 512; ++c) f += avL[c] * inp(lw2, (long)tid * 512 + c, isbf);
        feat[tid] = f;
    }
    __syncthreads();
    if (tid < 23) {
        float acc = 0.f;
        for (int e = 0; e < 8; ++e) {
            float d = inp(ebias, e * 23 + tid, isbf);
            for (int f = 0; f < 128; ++f) d += inp(ew, (e * 23 + tid) * 128 + f, isbf) * feat[f];
            acc += gates[e] * d;
        }
        outw(out, OUT_LOGITS + b * 23 + tid, acc, isbf);
    }
}

extern "C" void kernel_launch(void* const* d_in, const int* in_sizes, int n_in,
                              void* d_out, int out_size, void* d_ws, size_t ws_size,
                              hipStream_t stream) {
    (void)in_sizes; (void)n_in; (void)out_size; (void)ws_size;
    const void* img   = d_in[0];
    const void* state = d_in[2];
    const void* Wt    = d_in[4];
    const void* cw1   = d_in[7];
    const void* g1    = d_in[8];
    const void* bb1   = d_in[9];
    const void* cw2   = d_in[10];
    const void* g2    = d_in[11];
    const void* bb2   = d_in[12];
    const void* w3    = d_in[13];
    const void* b3    = d_in[14];
    const void* txtw  = d_in[15];
    const void* txtb  = d_in[16];
    const void* lnw   = d_in[17];
    const void* lnb   = d_in[18];
    const void* lnw2  = d_in[19];
    const void* lnb2  = d_in[20];
    const void* rw1   = d_in[21];
    const void* rb1   = d_in[22];
    const void* rw2   = d_in[23];
    const void* rb2   = d_in[24];
    const void* ew    = d_in[25];
    const void* eb    = d_in[26];

    char* ws = (char*)d_ws;
    __hip_bfloat16* A    = (__hip_bfloat16*)(ws + WS_A);
    float*          SRCN = (float*)(ws + WS_SRCN);
    __hip_bfloat16* WTB  = (__hip_bfloat16*)(ws + WS_WTB);
    __hip_bfloat16* WR1  = (__hip_bfloat16*)(ws + WS_WR1);
    __hip_bfloat16* WR2  = (__hip_bfloat16*)(ws + WS_WR2);
    __hip_bfloat16* SRCB = (__hip_bfloat16*)(ws + WS_SRCB);
    __hip_bfloat16* Y1   = (__hip_bfloat16*)(ws + WS_Y1);
    __hip_bfloat16* Y2   = (__hip_bfloat16*)(ws + WS_Y2);
    float* S1A = (float*)(ws + WS_STATS);
    float* S2A = S1A + 512;
    float* S1B = S1A + 1024;
    float* S2B = S1A + 1536;
    float* ANS   = (float*)(ws + WS_ANS);
    float* ANSV  = (float*)(ws + WS_ANSV);
    float* QA    = (float*)(ws + WS_QA);
    float* WORD  = (float*)(ws + WS_WORD);
    float* WORD2 = (float*)(ws + WS_WORD2);
    float* EFFW  = (float*)(ws + WS_EFFW);
    float* EFFB  = (float*)(ws + WS_EFFB);
    int*   DFL   = (int*)(ws + WS_FLAG);

    hipMemsetAsync(ws + WS_STATS, 0, 4 * 512 * sizeof(float), stream);

    k_detect<<<1, 256, 0, stream>>>(img, DFL);
    k_buildA<<<4096, dim3(32, 8), 0, stream>>>(img, A, DFL);
    k_prep<<<1792, 256, 0, stream>>>(cw1, cw2, Wt, WR1, WR2, WTB, DFL);
    k_gemm1<<<dim3(64, 4), 256, 0, stream>>>(A, WTB, SRCN, SRCB);
    k_src_out<<<4096, dim3(32, 8), 0, stream>>>(SRCN, d_out, DFL);
    k_ans<<<64, 256, 0, stream>>>(SRCN, ANS);
    k_answord<<<8, 256, 0, stream>>>(ANS, lnw, lnb, state, ANSV, QA, WORD, DFL);
    k_txt<<<2305, 256, 0, stream>>>(WORD, txtw, txtb, WORD2, DFL);
    k_eff<<<72, 256, 0, stream>>>(WORD2, w3, b3, EFFW, EFFB, DFL);
    // conv1: src(32x32x512) -up2x-> 64x64 -> 3x3 conv -> y1(64x64x512)
    k_conv_up3<<<dim3(256, 4), 512, 0, stream>>>(SRCB, WR1, Y1, 32, 32, 512);
    k_stats<<<512, 256, 0, stream>>>(Y1, S1A, S2A, 512, 32768);
    k_bn<<<2048, 256, 0, stream>>>(Y1, S1A, S2A, g1, bb1, 512, 16777216L, 1.f / 32768.f, DFL);
    // conv2: x1(64x64x512) -up2x-> 128x128 -> 3x3 conv -> y2(128x128x256)
    k_conv_up3<<<dim3(1024, 2), 512, 0, stream>>>(Y1, WR2, Y2, 64, 64, 256);
    k_stats<<<256, 256, 0, stream>>>(Y2, S1B, S2B, 256, 131072);
    k_bn<<<2048, 256, 0, stream>>>(Y2, S1B, S2B, g2, bb2, 256, 33554432L, 1.f / 131072.f, DFL);
    k_masks<<<2048, 256, 0, stream>>>(Y2, EFFW, EFFB, WORD2, d_out, DFL);
    k_router<<<8, 256, 0, stream>>>(QA, ANSV, rw1, rb1, rw2, rb2, lnw2, lnb2, ew, eb, d_out, DFL);
}

// Round 6
// 1659.615 us; speedup vs baseline: 1.2019x; 1.2019x over previous
//
#include <hip/hip_runtime.h>
#include <hip/hip_bf16.h>

typedef __attribute__((ext_vector_type(8))) short short8;
typedef __attribute__((ext_vector_type(4))) short shortx4;
typedef __attribute__((ext_vector_type(4))) float floatx4;

#define F2BF __float2bfloat16
#define BF2F __bfloat162float

// ---------------- workspace layout (byte offsets), total ~125.3 MiB ----------------
#define WS_A      0UL                // bf16 A [8192][512]  (img^T + pe)
#define WS_WTB    8388608UL          // bf16 W_t cast [512][512]
#define WS_WR1    8912896UL          // bf16 conv1 w repacked [9][512][512]
#define WS_WR2    13631488UL         // bf16 conv2 w repacked [9][256][512]
#define WS_SRCB   15990784UL         // bf16 src NHWC [8192][512]
#define WS_Y1     24379392UL         // bf16 y1 RAW (pre-bn) [8][64][64][512]
#define WS_Y2     57933824UL         // bf16 y2 RAW (pre-bn) [8][128][128][256]
#define WS_STATS  125042688UL        // f32 [4][512] (s1A,s2A,s1B,s2B)  -- zeroed
#define WS_ANS    125050880UL        // f32 [8][512] column SUMS        -- zeroed
#define WS_QA     125067264UL        // f32 [8][1024]
#define WS_ANSV   125100032UL        // f32 [8][512]
#define WS_WORD   125116416UL        // f32 [8][512]
#define WS_WORD2  125132800UL        // f32 [8][2305]
#define WS_EFFW   125206560UL        // f32 [8][9][256]
#define WS_EFFB   125280288UL        // f32 [8][9]

// d_out element offsets: masks [0,131072) ; logits [131072,131256) ; src [131256,...)
#define OUT_LOGITS 131072
#define OUT_SRC    131256

// ---- dual-dtype input read / output write ----
__device__ __forceinline__ float inp(const void* p, long i, int isbf) {
    return isbf ? BF2F(((const __hip_bfloat16*)p)[i]) : ((const float*)p)[i];
}
__device__ __forceinline__ void outw(void* p, long i, float v, int isbf) {
    if (isbf) ((__hip_bfloat16*)p)[i] = F2BF(v);
    else      ((float*)p)[i] = v;
}
__device__ __forceinline__ float bfbits2f(short s) {
    unsigned int u = ((unsigned int)(unsigned short)s) << 16;
    float f; __builtin_memcpy(&f, &u, 4); return f;
}
__device__ __forceinline__ short f2bfbits(float f) {
    __hip_bfloat16 h = F2BF(f);
    short s; __builtin_memcpy(&s, &h, 2); return s;
}

// ---- inline per-wave dtype detect (round-3-validated statistic; 512 samples, 22-sigma) ----
__device__ __forceinline__ int detect_bf(const void* img) {
    const unsigned short* u = (const unsigned short*)img;
    int l = threadIdx.x & 63;
    int c = 0;
#pragma unroll
    for (int k = 0; k < 8; ++k) {
        int e = (u[(l * 8 + k) * 2] >> 7) & 0xFF;
        c += (e >= 100 && e <= 150) ? 1 : 0;
    }
    for (int off = 32; off; off >>= 1) c += __shfl_xor(c, off, 64);
    return c > 307;   // 60% of 512
}

__device__ __forceinline__ float pe_val(int n, int c) {
    float pos = (c < 256) ? (float)(n & 31) : (float)(n >> 5);
    int i = ((c < 256) ? c : (c - 256)) >> 1;
    float ang = pos * expf(-0.0719557841560639f * (float)i);
    return (c & 1) ? cosf(ang) : sinf(ang);
}

// ---- fused prep: [0,4096) buildA ; [4096,5632) conv-w repack ; [5632,5888) Wt cast ----
__global__ void k_pre(const void* __restrict__ img, const void* __restrict__ cw1,
                      const void* __restrict__ cw2, const void* __restrict__ Wt,
                      __hip_bfloat16* __restrict__ A, __hip_bfloat16* __restrict__ WR1,
                      __hip_bfloat16* __restrict__ WR2, __hip_bfloat16* __restrict__ WTB) {
    int isbf = detect_bf(img);
    int bid = blockIdx.x, tid = threadIdx.x;
    __shared__ float LS[2304];
    if (bid < 4096) {
        int nt = bid & 31, ct = (bid >> 5) & 15, b = bid >> 9;
        int tx = tid & 31, ty = tid >> 5;
        int c0 = ct * 32, n0 = nt * 32;
        for (int j = 0; j < 4; ++j) {
            int c = c0 + ty + j * 8;
            LS[(ty + j * 8) * 33 + tx] = inp(img, ((long)(b * 512 + c)) * 1024 + n0 + tx, isbf);
        }
        __syncthreads();
        for (int j = 0; j < 4; ++j) {
            int n = n0 + ty + j * 8, c = c0 + tx;
            A[((long)(b * 1024 + n)) * 512 + c] = F2BF(LS[tx * 33 + ty + j * 8] + pe_val(n, c));
        }
    } else if (bid < 5632) {
        int bb = bid - 4096;
        const void* w; __hip_bfloat16* wR; int total_r, r0;
        if (bb < 1024) { w = cw1; wR = WR1; total_r = 512 * 512; r0 = bb * 256; }
        else           { w = cw2; wR = WR2; total_r = 256 * 512; r0 = (bb - 1024) * 256; }
        for (int e = tid; e < 2304; e += 256) LS[e] = inp(w, (long)r0 * 9 + e, isbf);
        __syncthreads();
#pragma unroll
        for (int tap = 0; tap < 9; ++tap)
            wR[(long)tap * total_r + r0 + tid] = F2BF(LS[tid * 9 + tap]);
    } else {
        for (int i = (bid - 5632) * 256 + tid; i < 512 * 512; i += 256 * 256)
            WTB[i] = F2BF(inp(Wt, i, isbf));
    }
}

// ---- MFMA GEMM + fused epilogue: SRCB, d_out src (packed hw-stores), ANS col-sums ----
__global__ __launch_bounds__(256) void k_gemm1(const __hip_bfloat16* __restrict__ A,
                                               const __hip_bfloat16* __restrict__ Bw,
                                               __hip_bfloat16* __restrict__ srcB,
                                               void* __restrict__ dst,
                                               float* __restrict__ ANS,
                                               const void* __restrict__ img) {
    int isbf = detect_bf(img);
    __shared__ __align__(16) __hip_bfloat16 As[128 * 32];
    __shared__ __align__(16) __hip_bfloat16 Bs[128 * 32];
    int m0 = blockIdx.x * 128, n0 = blockIdx.y * 128;
    int tid = threadIdx.x;
    int wave = tid >> 6, l = tid & 63, lm = l & 15, q = l >> 4;
    int wm = wave & 1, wn = wave >> 1;
    floatx4 zero4 = {0.f, 0.f, 0.f, 0.f};
    floatx4 acc[4][4];
    for (int i = 0; i < 4; ++i) for (int j = 0; j < 4; ++j) acc[i][j] = zero4;
    for (int k0 = 0; k0 < 512; k0 += 32) {
        __syncthreads();
        for (int s = tid; s < 512; s += 256) {
            int m = s >> 2, qq = s & 3;
            *(short8*)(As + m * 32 + qq * 8) = *(const short8*)(A + ((long)(m0 + m)) * 512 + k0 + qq * 8);
            *(short8*)(Bs + m * 32 + qq * 8) = *(const short8*)(Bw + ((long)(n0 + m)) * 512 + k0 + qq * 8);
        }
        __syncthreads();
        short8 af[4], bfv[4];
#pragma unroll
        for (int t = 0; t < 4; ++t) af[t] = *(short8*)(As + (wm * 64 + t * 16 + lm) * 32 + q * 8);
#pragma unroll
        for (int t = 0; t < 4; ++t) bfv[t] = *(short8*)(Bs + (wn * 64 + t * 16 + lm) * 32 + q * 8);
#pragma unroll
        for (int i = 0; i < 4; ++i)
#pragma unroll
            for (int j = 0; j < 4; ++j)
                acc[i][j] = __builtin_amdgcn_mfma_f32_16x16x32_bf16(af[i], bfv[j], acc[i][j], 0, 0, 0);
    }
    // epilogue
    int b = m0 >> 10, hw0 = m0 & 1023;
    float cs[4] = {0.f, 0.f, 0.f, 0.f};
#pragma unroll
    for (int i = 0; i < 4; ++i)
#pragma unroll
        for (int j = 0; j < 4; ++j) {
            int mrow = wm * 64 + i * 16 + q * 4;
            int n = n0 + wn * 64 + j * 16 + lm;
            long mg = (long)(m0 + mrow);
#pragma unroll
            for (int r = 0; r < 4; ++r) {
                float v = acc[i][j][r];
                srcB[(mg + r) * 512 + n] = F2BF(v);
                cs[j] += v;
            }
            long obase = (long)OUT_SRC + ((long)(b * 512 + n)) * 1024 + hw0 + mrow;
            if (isbf) {
                shortx4 pk = { f2bfbits(acc[i][j][0]), f2bfbits(acc[i][j][1]),
                               f2bfbits(acc[i][j][2]), f2bfbits(acc[i][j][3]) };
                *(shortx4*)((__hip_bfloat16*)dst + obase) = pk;
            } else {
                floatx4 pk = { acc[i][j][0], acc[i][j][1], acc[i][j][2], acc[i][j][3] };
                *(floatx4*)((float*)dst + obase) = pk;
            }
        }
#pragma unroll
    for (int j = 0; j < 4; ++j) {
        cs[j] += __shfl_xor(cs[j], 16);
        cs[j] += __shfl_xor(cs[j], 32);
    }
    __syncthreads();
    float* CS = (float*)Bs;   // reuse LDS
    if (wm == 1 && q == 0) {
#pragma unroll
        for (int j = 0; j < 4; ++j) CS[wn * 64 + j * 16 + lm] = cs[j];
    }
    __syncthreads();
    if (wm == 0 && q == 0) {
#pragma unroll
        for (int j = 0; j < 4; ++j) {
            int n = n0 + wn * 64 + j * 16 + lm;
            atomicAdd(ANS + b * 512 + n, cs[j] + CS[wn * 64 + j * 16 + lm]);
        }
    }
}

// ---- fused: ans_vec (ANS sums/1024 @ lnW^T + lnb); qa; word = softmax(qa)*qa folded ----
__global__ void k_answord(const float* __restrict__ ANS, const void* __restrict__ lw,
                          const void* __restrict__ lb, const void* __restrict__ state,
                          float* __restrict__ ansv, float* __restrict__ qa,
                          float* __restrict__ word, const void* __restrict__ img) {
    int isbf = detect_bf(img);
    int b = blockIdx.x, tid = threadIdx.x;
    __shared__ float aL[512];
    __shared__ float L[1024];
    __shared__ float red[256];
    aL[tid] = ANS[b * 512 + tid] * (1.f / 1024.f);
    aL[tid + 256] = ANS[b * 512 + tid + 256] * (1.f / 1024.f);
    __syncthreads();
    for (int d = tid; d < 512; d += 256) {
        float acc = inp(lb, d, isbf);
        for (int c = 0; c < 512; ++c) acc += aL[c] * inp(lw, (long)d * 512 + c, isbf);
        ansv[b * 512 + d] = acc;
        qa[b * 1024 + 512 + d] = acc;
        L[512 + d] = acc;
    }
    float s0 = inp(state, b * 512 + tid, isbf);
    float s1 = inp(state, b * 512 + tid + 256, isbf);
    qa[b * 1024 + tid] = s0;
    qa[b * 1024 + tid + 256] = s1;
    L[tid] = s0;
    L[tid + 256] = s1;
    __syncthreads();
    float m = fmaxf(fmaxf(L[tid], L[tid + 256]), fmaxf(L[tid + 512], L[tid + 768]));
    red[tid] = m; __syncthreads();
    for (int s = 128; s > 0; s >>= 1) { if (tid < s) red[tid] = fmaxf(red[tid], red[tid + s]); __syncthreads(); }
    float M = red[0]; __syncthreads();
    float z = expf(L[tid] - M) + expf(L[tid + 256] - M) + expf(L[tid + 512] - M) + expf(L[tid + 768] - M);
    red[tid] = z; __syncthreads();
    for (int s = 128; s > 0; s >>= 1) { if (tid < s) red[tid] += red[tid + s]; __syncthreads(); }
    float Z = red[0];
    for (int j = tid; j < 512; j += 256) {
        float o1 = expf(L[j] - M) / Z * L[j];
        float o2 = expf(L[j + 512] - M) / Z * L[j + 512];
        word[b * 512 + j] = o1 + o2;
    }
}

// ---- word2[b][n] = word@txt_w^T + txt_b ----
__global__ void k_txt(const float* __restrict__ word, const void* __restrict__ tw,
                      const void* __restrict__ tb, float* __restrict__ word2,
                      const void* __restrict__ img) {
    int isbf = detect_bf(img);
    int n = blockIdx.x, tid = threadIdx.x;
    __shared__ float wL[8][512];
    __shared__ float red[256 * 8];
    for (int e = tid; e < 4096; e += 256) wL[e >> 9][e & 511] = word[e];
    __syncthreads();
    float acc[8] = {0, 0, 0, 0, 0, 0, 0, 0};
    for (int c = tid; c < 512; c += 256) {
        float tv = inp(tw, (long)n * 512 + c, isbf);
        for (int b = 0; b < 8; ++b) acc[b] += wL[b][c] * tv;
    }
    for (int b = 0; b < 8; ++b) red[tid * 8 + b] = acc[b];
    __syncthreads();
    for (int s = 128; s > 0; s >>= 1) {
        if (tid < s) for (int b = 0; b < 8; ++b) red[tid * 8 + b] += red[(tid + s) * 8 + b];
        __syncthreads();
    }
    if (tid < 8) word2[tid * 2305 + n] = red[tid] + inp(tb, n, isbf);
}

// ---- eff_w[b][tap][c2] = sum_cx dyn_w[b][cx][tap]*w3[cx][c2]; effb ----
__global__ void k_eff(const float* __restrict__ word2, const void* __restrict__ w3,
                      const void* __restrict__ b3, float* __restrict__ effw,
                      float* __restrict__ effb, const void* __restrict__ img) {
    int isbf = detect_bf(img);
    int bid = blockIdx.x;
    int b = bid / 9, tap = bid - b * 9;
    int tid = threadIdx.x;
    __shared__ float dw[256];
    dw[tid] = word2[b * 2305 + tid * 9 + tap];
    __syncthreads();
    float acc = 0.f;
    for (int c = 0; c < 256; ++c) acc += dw[c] * inp(w3, c * 256 + tid, isbf);
    effw[(b * 9 + tap) * 256 + tid] = acc;
    if (tid == 0) {
        float e = 0.f;
        for (int c = 0; c < 256; ++c) e += dw[c] * inp(b3, c, isbf);
        effb[b * 9 + tap] = e;
    }
}

// ---- conv (round-4 tiling) + optional inline input-bn + fused stats epilogue ----
// 3x3 pad1 on 2x-bilinear-upsampled NHWC bf16 input, Cin=512, bf16 MFMA.
__global__ __launch_bounds__(256) void k_conv(const __hip_bfloat16* __restrict__ in,
                                              const __hip_bfloat16* __restrict__ wRb,
                                              __hip_bfloat16* __restrict__ out,
                                              int inH, int inW, int Cout,
                                              float* __restrict__ s1o, float* __restrict__ s2o,
                                              const float* __restrict__ bnS1,
                                              const float* __restrict__ bnS2,
                                              const void* __restrict__ g,
                                              const void* __restrict__ bb, float invN,
                                              const void* __restrict__ img) {
    int OH = inH * 2, OW = inW * 2;
    int tXn = OW >> 4, tYn = OH >> 3;
    int bid = blockIdx.x;
    int tX = bid % tXn; int tmp = bid / tXn; int tY = tmp % tYn; int b = tmp / tYn;
    int co0 = blockIdx.y * 128;
    __shared__ __align__(16) __hip_bfloat16 Os[60 * 32];
    __shared__ __align__(16) __hip_bfloat16 Ah[180 * 32];
    __shared__ float scT[512];
    __shared__ float shT[512];
    int tid = threadIdx.x;
    int wave = tid >> 6, l = tid & 63, lm = l & 15, q = l >> 4;
    int wm = wave & 1, wn = wave >> 1;
    int dobn = (bnS1 != nullptr);
    if (dobn) {
        int isbf = detect_bf(img);
        for (int c = tid; c < 512; c += 256) {
            float m = bnS1[c] * invN, var = bnS2[c] * invN - m * m;
            float sc = inp(g, c, isbf) * rsqrtf(var + 1e-5f);
            scT[c] = sc; shT[c] = inp(bb, c, isbf) - m * sc;
        }
    }
    int R0m1 = (tY << 2) - 1;
    int C0m1 = (tX << 3) - 1;
    floatx4 zero4 = {0.f, 0.f, 0.f, 0.f};
    floatx4 acc[4][4];
    for (int i = 0; i < 4; ++i) for (int j = 0; j < 4; ++j) acc[i][j] = zero4;

    for (int ci0 = 0; ci0 < 512; ci0 += 32) {
        __syncthreads();
        if (tid < 240) {
            int p = tid >> 2, sub = tid & 3;
            int r = p / 10, cx = p - r * 10;
            int gr = R0m1 + r; gr = gr < 0 ? 0 : (gr > inH - 1 ? inH - 1 : gr);
            int gc = C0m1 + cx; gc = gc < 0 ? 0 : (gc > inW - 1 ? inW - 1 : gc);
            short8 raw = *(const short8*)(in + ((long)(b * inH + gr) * inW + gc) * 512 + ci0 + sub * 8);
            if (dobn) {
#pragma unroll
                for (int k = 0; k < 8; ++k) {
                    int c = ci0 + sub * 8 + k;
                    float v = bfbits2f(raw[k]) * scT[c] + shT[c];
                    raw[k] = f2bfbits(v > 0.f ? v : 0.f);
                }
            }
            *(short8*)(Os + p * 32 + sub * 8) = raw;
        }
        __syncthreads();
        for (int e = tid; e < 720; e += 256) {
            int p = e >> 2, sub = e & 3;
            int hy = p / 18, hx = p - hy * 18;
            int gy = (tY << 3) + hy - 1, gx = (tX << 4) + hx - 1;
            short8 res = {0, 0, 0, 0, 0, 0, 0, 0};
            if (gy >= 0 && gy < OH && gx >= 0 && gx < OW) {
                int r0; float wy0;
                if (gy & 1) { r0 = gy >> 1; wy0 = 0.75f; } else { r0 = (gy >> 1) - 1; wy0 = 0.25f; }
                int r1 = r0 + 1;
                if (r0 < 0) r0 = 0; if (r1 > inH - 1) r1 = inH - 1;
                int s0; float wx0;
                if (gx & 1) { s0 = gx >> 1; wx0 = 0.75f; } else { s0 = (gx >> 1) - 1; wx0 = 0.25f; }
                int s1 = s0 + 1;
                if (s0 < 0) s0 = 0; if (s1 > inW - 1) s1 = inW - 1;
                int lr0 = r0 - R0m1, lr1 = r1 - R0m1;
                int lc0 = s0 - C0m1, lc1 = s1 - C0m1;
                float wy1 = 1.f - wy0, wx1 = 1.f - wx0;
                float w00 = wy0 * wx0, w01 = wy0 * wx1, w10 = wy1 * wx0, w11 = wy1 * wx1;
                short8 v00 = *(const short8*)(Os + (lr0 * 10 + lc0) * 32 + sub * 8);
                short8 v01 = *(const short8*)(Os + (lr0 * 10 + lc1) * 32 + sub * 8);
                short8 v10 = *(const short8*)(Os + (lr1 * 10 + lc0) * 32 + sub * 8);
                short8 v11 = *(const short8*)(Os + (lr1 * 10 + lc1) * 32 + sub * 8);
#pragma unroll
                for (int k = 0; k < 8; ++k) {
                    float f = w00 * bfbits2f(v00[k]) + w01 * bfbits2f(v01[k]) +
                              w10 * bfbits2f(v10[k]) + w11 * bfbits2f(v11[k]);
                    res[k] = f2bfbits(f);
                }
            }
            *(short8*)(Ah + p * 32 + sub * 8) = res;
        }
        __syncthreads();
#pragma unroll
        for (int tap = 0; tap < 9; ++tap) {
            int ky = tap / 3, kx = tap - ky * 3;
            short8 bfv[4];
#pragma unroll
            for (int t = 0; t < 4; ++t)
                bfv[t] = *(const short8*)(wRb + ((long)(tap * Cout + co0 + wn * 64 + t * 16 + lm)) * 512 + ci0 + q * 8);
            short8 af[4];
#pragma unroll
            for (int t = 0; t < 4; ++t)
                af[t] = *(short8*)(Ah + ((wm * 4 + t + ky) * 18 + lm + kx) * 32 + q * 8);
#pragma unroll
            for (int i = 0; i < 4; ++i)
#pragma unroll
                for (int j = 0; j < 4; ++j)
                    acc[i][j] = __builtin_amdgcn_mfma_f32_16x16x32_bf16(af[i], bfv[j], acc[i][j], 0, 0, 0);
        }
    }
    // epilogue: store (round-4 pattern) + per-channel stats partials
    float s1v[4] = {0.f, 0.f, 0.f, 0.f}, s2v[4] = {0.f, 0.f, 0.f, 0.f};
#pragma unroll
    for (int i = 0; i < 4; ++i) {
        int py = wm * 4 + i;
#pragma unroll
        for (int j = 0; j < 4; ++j) {
            int cob = co0 + wn * 64 + j * 16 + lm;
#pragma unroll
            for (int r = 0; r < 4; ++r) {
                int pxc = q * 4 + r;
                int oy = (tY << 3) + py, ox = (tX << 4) + pxc;
                float v = acc[i][j][r];
                out[(((long)(b * OH + oy)) * OW + ox) * Cout + cob] = F2BF(v);
                s1v[j] += v; s2v[j] += v * v;
            }
        }
    }
#pragma unroll
    for (int j = 0; j < 4; ++j) {
        s1v[j] += __shfl_xor(s1v[j], 16); s1v[j] += __shfl_xor(s1v[j], 32);
        s2v[j] += __shfl_xor(s2v[j], 16); s2v[j] += __shfl_xor(s2v[j], 32);
    }
    __syncthreads();
    float* RB = (float*)Ah;   // reuse LDS: [0,128)=s1 partials, [128,256)=s2
    if (wm == 1 && q == 0) {
#pragma unroll
        for (int j = 0; j < 4; ++j) {
            int idx = wn * 64 + j * 16 + lm;
            RB[idx] = s1v[j]; RB[128 + idx] = s2v[j];
        }
    }
    __syncthreads();
    if (wm == 0 && q == 0) {
#pragma unroll
        for (int j = 0; j < 4; ++j) {
            int idx = wn * 64 + j * 16 + lm;
            atomicAdd(s1o + co0 + idx, s1v[j] + RB[idx]);
            atomicAdd(s2o + co0 + idx, s2v[j] + RB[128 + idx]);
        }
    }
}

// ---- masks: inline bn2+relu on raw Y2, then fused (conv3 ∘ dyn conv) via eff_w ----
__global__ __launch_bounds__(256) void k_masks(const __hip_bfloat16* __restrict__ x2,
                                               const float* __restrict__ effw,
                                               const float* __restrict__ effb,
                                               const float* __restrict__ word2,
                                               void* __restrict__ mout,
                                               const float* __restrict__ s1,
                                               const float* __restrict__ s2,
                                               const void* __restrict__ g,
                                               const void* __restrict__ bb, float invN,
                                               const void* __restrict__ img) {
    int isbf = detect_bf(img);
    int bid = blockIdx.x;
    int tX = bid & 15, tY = (bid >> 4) & 15, b = bid >> 8;
    __shared__ __align__(16) __hip_bfloat16 H[100 * 264];
    __shared__ __align__(16) float EW[9 * 256];
    __shared__ float EB[9];
    __shared__ float sc2T[256];
    __shared__ float sh2T[256];
    int tid = threadIdx.x;
    {
        float m = s1[tid] * invN, var = s2[tid] * invN - m * m;
        float sc = inp(g, tid, isbf) * rsqrtf(var + 1e-5f);
        sc2T[tid] = sc; sh2T[tid] = inp(bb, tid, isbf) - m * sc;
    }
    __syncthreads();
    for (int e = tid; e < 25600; e += 256) {
        int c = e & 255, p = e >> 8;
        int hy = p / 10, hx = p - hy * 10;
        int gy = tY * 8 + hy - 1, gx = tX * 8 + hx - 1;
        float v = 0.f;
        if (gy >= 0 && gy < 128 && gx >= 0 && gx < 128) {
            float raw = BF2F(x2[(((long)(b * 128 + gy)) * 128 + gx) * 256 + c]);
            v = raw * sc2T[c] + sh2T[c];
            v = v > 0.f ? v : 0.f;
        }
        H[p * 264 + c] = F2BF(v);
    }
    for (int e = tid; e < 2304; e += 256) EW[e] = effw[b * 2304 + e];
    if (tid < 9) EB[tid] = effb[b * 9 + tid];
    __syncthreads();
    int px = tid & 63, part = tid >> 6;
    int py = px >> 3, pxc = px & 7;
    int cbase = part * 64;
    float acc = 0.f;
    for (int tap = 0; tap < 9; ++tap) {
        int ky = tap / 3, kx = tap - ky * 3;
        int hp = (py + ky) * 10 + pxc + kx;
        const __hip_bfloat16* hrow = H + (long)hp * 264 + cbase;
        const float* erow = EW + tap * 256 + cbase;
#pragma unroll
        for (int c8 = 0; c8 < 8; ++c8) {
            short8 h8 = *(const short8*)(hrow + c8 * 8);
            floatx4 e0 = *(const floatx4*)(erow + c8 * 8);
            floatx4 e1 = *(const floatx4*)(erow + c8 * 8 + 4);
            acc += bfbits2f(h8[0]) * e0[0] + bfbits2f(h8[1]) * e0[1] +
                   bfbits2f(h8[2]) * e0[2] + bfbits2f(h8[3]) * e0[3] +
                   bfbits2f(h8[4]) * e1[0] + bfbits2f(h8[5]) * e1[1] +
                   bfbits2f(h8[6]) * e1[2] + bfbits2f(h8[7]) * e1[3];
        }
    }
    float (*red)[64] = (float(*)[64])sc2T;   // sc2T/sh2T dead after staging (barrier passed)
    red[part][px] = acc;
    __syncthreads();
    if (part == 0) {
        float s = red[0][px] + red[1][px] + red[2][px] + red[3][px];
        int oy = tY * 8 + py, ox = tX * 8 + pxc;
        float bias = word2[b * 2305 + 2304];
        for (int tap = 0; tap < 9; ++tap) {
            int ky = tap / 3, kx = tap - ky * 3;
            int iy = oy + ky - 1, ix = ox + kx - 1;
            if (iy >= 0 && iy < 128 && ix >= 0 && ix < 128) bias += EB[tap];
        }
        outw(mout, b * 16384 + oy * 128 + ox, s + bias, isbf);
    }
}

// ---- router/gates/experts -> logits ----
__global__ void k_router(const float* __restrict__ qa, const float* __restrict__ ansv,
                         const void* __restrict__ w1, const void* __restrict__ b1,
                         const void* __restrict__ w2, const void* __restrict__ b2,
                         const void* __restrict__ lw2, const void* __restrict__ lb2,
                         const void* __restrict__ ew, const void* __restrict__ ebias,
                         void* __restrict__ out, const void* __restrict__ img) {
    int isbf = detect_bf(img);
    int b = blockIdx.x, tid = threadIdx.x;
    __shared__ float qL[1024], hid[256], gates[8], feat[128], avL[512];
    for (int j = tid; j < 1024; j += 256) qL[j] = qa[b * 1024 + j];
    for (int j = tid; j < 512; j += 256) avL[j] = ansv[b * 512 + j];
    __syncthreads();
    float h = inp(b1, tid, isbf);
    for (int k = 0; k < 1024; ++k) h += qL[k] * inp(w1, (long)tid * 1024 + k, isbf);
    hid[tid] = h > 0.f ? h : 0.f;
    __syncthreads();
    if (tid < 8) {
        float gl = inp(b2, tid, isbf);
        for (int j = 0; j < 256; ++j) gl += hid[j] * inp(w2, tid * 256 + j, isbf);
        gates[tid] = gl;
    }
    __syncthreads();
    if (tid == 0) {
        float mx = gates[0];
        for (int e = 1; e < 8; ++e) mx = fmaxf(mx, gates[e]);
        float z = 0.f;
        for (int e = 0; e < 8; ++e) { gates[e] = expf(gates[e] - mx); z += gates[e]; }
        for (int e = 0; e < 8; ++e) gates[e] /= z;
    }
    if (tid < 128) {
        float f = inp(lb2, tid, isbf);
        for (int c = 0; c < 512; ++c) f += avL[c] * inp(lw2, (long)tid * 512 + c, isbf);
        feat[tid] = f;
    }
    __syncthreads();
    if (tid < 23) {
        float acc = 0.f;
        for (int e = 0; e < 8; ++e) {
            float d = inp(ebias, e * 23 + tid, isbf);
            for (int f = 0; f < 128; ++f) d += inp(ew, (e * 23 + tid) * 128 + f, isbf) * feat[f];
            acc += gates[e] * d;
        }
        outw(out, OUT_LOGITS + b * 23 + tid, acc, isbf);
    }
}

extern "C" void kernel_launch(void* const* d_in, const int* in_sizes, int n_in,
                              void* d_out, int out_size, void* d_ws, size_t ws_size,
                              hipStream_t stream) {
    (void)in_sizes; (void)n_in; (void)out_size; (void)ws_size;
    const void* img   = d_in[0];
    const void* state = d_in[2];
    const void* Wt    = d_in[4];
    const void* cw1   = d_in[7];
    const void* g1    = d_in[8];
    const void* bb1   = d_in[9];
    const void* cw2   = d_in[10];
    const void* g2    = d_in[11];
    const void* bb2   = d_in[12];
    const void* w3    = d_in[13];
    const void* b3    = d_in[14];
    const void* txtw  = d_in[15];
    const void* txtb  = d_in[16];
    const void* lnw   = d_in[17];
    const void* lnb   = d_in[18];
    const void* lnw2  = d_in[19];
    const void* lnb2  = d_in[20];
    const void* rw1   = d_in[21];
    const void* rb1   = d_in[22];
    const void* rw2   = d_in[23];
    const void* rb2   = d_in[24];
    const void* ew    = d_in[25];
    const void* eb    = d_in[26];

    char* ws = (char*)d_ws;
    __hip_bfloat16* A    = (__hip_bfloat16*)(ws + WS_A);
    __hip_bfloat16* WTB  = (__hip_bfloat16*)(ws + WS_WTB);
    __hip_bfloat16* WR1  = (__hip_bfloat16*)(ws + WS_WR1);
    __hip_bfloat16* WR2  = (__hip_bfloat16*)(ws + WS_WR2);
    __hip_bfloat16* SRCB = (__hip_bfloat16*)(ws + WS_SRCB);
    __hip_bfloat16* Y1   = (__hip_bfloat16*)(ws + WS_Y1);
    __hip_bfloat16* Y2   = (__hip_bfloat16*)(ws + WS_Y2);
    float* S1A = (float*)(ws + WS_STATS);
    float* S2A = S1A + 512;
    float* S1B = S1A + 1024;
    float* S2B = S1A + 1536;
    float* ANS   = (float*)(ws + WS_ANS);
    float* QA    = (float*)(ws + WS_QA);
    float* ANSV  = (float*)(ws + WS_ANSV);
    float* WORD  = (float*)(ws + WS_WORD);
    float* WORD2 = (float*)(ws + WS_WORD2);
    float* EFFW  = (float*)(ws + WS_EFFW);
    float* EFFB  = (float*)(ws + WS_EFFB);

    // zero stats (8 KB) + ANS sums (16 KB), contiguous
    hipMemsetAsync(ws + WS_STATS, 0, 24576, stream);

    k_pre<<<5888, 256, 0, stream>>>(img, cw1, cw2, Wt, A, WR1, WR2, WTB);
    k_gemm1<<<dim3(64, 4), 256, 0, stream>>>(A, WTB, SRCB, d_out, ANS, img);
    k_answord<<<8, 256, 0, stream>>>(ANS, lnw, lnb, state, ANSV, QA, WORD, img);
    k_txt<<<2305, 256, 0, stream>>>(WORD, txtw, txtb, WORD2, img);
    k_eff<<<72, 256, 0, stream>>>(WORD2, w3, b3, EFFW, EFFB, img);
    // conv1: src -up2x-> 64x64 -> 3x3 -> Y1 raw ; stats -> S1A/S2A
    k_conv<<<dim3(256, 4), 256, 0, stream>>>(SRCB, WR1, Y1, 32, 32, 512, S1A, S2A,
                                             nullptr, nullptr, nullptr, nullptr, 0.f, img);
    // conv2: bn1(Y1)+relu inline -up2x-> 128x128 -> 3x3 -> Y2 raw ; stats -> S1B/S2B
    k_conv<<<dim3(1024, 2), 256, 0, stream>>>(Y1, WR2, Y2, 64, 64, 256, S1B, S2B,
                                              S1A, S2A, g1, bb1, 1.f / 32768.f, img);
    // masks: bn2(Y2)+relu inline, fused dyn conv
    k_masks<<<2048, 256, 0, stream>>>(Y2, EFFW, EFFB, WORD2, d_out,
                                      S1B, S2B, g2, bb2, 1.f / 131072.f, img);
    k_router<<<8, 256, 0, stream>>>(QA, ANSV, rw1, rb1, rw2, rb2, lnw2, lnb2, ew, eb, d_out, img);
}

// Round 7
// 1290.901 us; speedup vs baseline: 1.5452x; 1.2856x over previous
//
#include <hip/hip_runtime.h>
#include <hip/hip_bf16.h>

typedef __attribute__((ext_vector_type(8))) short short8;
typedef __attribute__((ext_vector_type(4))) short shortx4;
typedef __attribute__((ext_vector_type(4))) float floatx4;

#define F2BF __float2bfloat16
#define BF2F __bfloat162float

// ---------------- workspace layout (byte offsets), total ~125.3 MiB ----------------
#define WS_A      0UL                // bf16 A [8192][512]  (img^T + pe)
#define WS_WTB    8388608UL          // bf16 W_t cast [512][512]
#define WS_WR1    8912896UL          // bf16 conv1 w [tap][cc][co][32]
#define WS_WR2    13631488UL         // bf16 conv2 w [tap][cc][co][32]
#define WS_SRCB   15990784UL         // bf16 src NHWC [8192][512]
#define WS_Y1     24379392UL         // bf16 y1 RAW (pre-bn) [8][64][64][512]
#define WS_Y2     57933824UL         // bf16 y2 RAW (pre-bn) [8][128][128][256]
#define WS_STATS  125042688UL        // f32 [4][512] (s1A,s2A,s1B,s2B)  -- zeroed
#define WS_ANS    125050880UL        // f32 [8][512] column SUMS        -- zeroed
#define WS_QA     125067264UL        // f32 [8][1024]
#define WS_ANSV   125100032UL        // f32 [8][512]
#define WS_WORD   125116416UL        // f32 [8][512]
#define WS_WORD2  125132800UL        // f32 [8][2305]
#define WS_EFFW   125206560UL        // f32 [8][9][256]
#define WS_EFFB   125280288UL        // f32 [8][9]
#define WS_HID    125280640UL        // f32 [8][256]

// d_out element offsets: masks [0,131072) ; logits [131072,131256) ; src [131256,...)
#define OUT_LOGITS 131072
#define OUT_SRC    131256

__device__ __forceinline__ float inp(const void* p, long i, int isbf) {
    return isbf ? BF2F(((const __hip_bfloat16*)p)[i]) : ((const float*)p)[i];
}
__device__ __forceinline__ void outw(void* p, long i, float v, int isbf) {
    if (isbf) ((__hip_bfloat16*)p)[i] = F2BF(v);
    else      ((float*)p)[i] = v;
}
__device__ __forceinline__ float bfbits2f(short s) {
    unsigned int u = ((unsigned int)(unsigned short)s) << 16;
    float f; __builtin_memcpy(&f, &u, 4); return f;
}
__device__ __forceinline__ short f2bfbits(float f) {
    __hip_bfloat16 h = F2BF(f);
    short s; __builtin_memcpy(&s, &h, 2); return s;
}

// ---- inline per-wave dtype detect (round-3-validated statistic) ----
__device__ __forceinline__ int detect_bf(const void* img) {
    const unsigned short* u = (const unsigned short*)img;
    int l = threadIdx.x & 63;
    int c = 0;
#pragma unroll
    for (int k = 0; k < 8; ++k) {
        int e = (u[(l * 8 + k) * 2] >> 7) & 0xFF;
        c += (e >= 100 && e <= 150) ? 1 : 0;
    }
    for (int off = 32; off; off >>= 1) c += __shfl_xor(c, off, 64);
    return c > 307;
}

__device__ __forceinline__ float pe_val(int n, int c) {
    float pos = (c < 256) ? (float)(n & 31) : (float)(n >> 5);
    int i = ((c < 256) ? c : (c - 256)) >> 1;
    float ang = pos * expf(-0.0719557841560639f * (float)i);
    return (c & 1) ? cosf(ang) : sinf(ang);
}

// ---- fused prep: [0,4096) buildA ; [4096,5632) conv-w repack ; [5632,5888) Wt cast ----
__global__ void k_pre(const void* __restrict__ img, const void* __restrict__ cw1,
                      const void* __restrict__ cw2, const void* __restrict__ Wt,
                      __hip_bfloat16* __restrict__ A, __hip_bfloat16* __restrict__ WR1,
                      __hip_bfloat16* __restrict__ WR2, __hip_bfloat16* __restrict__ WTB) {
    int isbf = detect_bf(img);
    int bid = blockIdx.x, tid = threadIdx.x;
    __shared__ float LS[2304];
    if (bid < 4096) {
        int nt = bid & 31, ct = (bid >> 5) & 15, b = bid >> 9;
        int tx = tid & 31, ty = tid >> 5;
        int c0 = ct * 32, n0 = nt * 32;
        for (int j = 0; j < 4; ++j) {
            int c = c0 + ty + j * 8;
            LS[(ty + j * 8) * 33 + tx] = inp(img, ((long)(b * 512 + c)) * 1024 + n0 + tx, isbf);
        }
        __syncthreads();
        for (int j = 0; j < 4; ++j) {
            int n = n0 + ty + j * 8, c = c0 + tx;
            A[((long)(b * 1024 + n)) * 512 + c] = F2BF(LS[tx * 33 + ty + j * 8] + pe_val(n, c));
        }
    } else if (bid < 5632) {
        int bb = bid - 4096;
        const void* w; __hip_bfloat16* wR; int Cout, r0;
        if (bb < 1024) { w = cw1; wR = WR1; Cout = 512; r0 = bb * 256; }
        else           { w = cw2; wR = WR2; Cout = 256; r0 = (bb - 1024) * 256; }
        int co = r0 >> 9, ci0 = r0 & 511;
        for (int e = tid; e < 2304; e += 256) LS[e] = inp(w, (long)r0 * 9 + e, isbf);
        __syncthreads();
        int ci = ci0 + tid;
        int cc = ci >> 5, cw = ci & 31;
#pragma unroll
        for (int tap = 0; tap < 9; ++tap)
            wR[((long)(tap * 16 + cc) * Cout + co) * 32 + cw] = F2BF(LS[tid * 9 + tap]);
    } else {
        for (int i = (bid - 5632) * 256 + tid; i < 512 * 512; i += 256 * 256)
            WTB[i] = F2BF(inp(Wt, i, isbf));
    }
}

// ---- MFMA GEMM + fused epilogue: SRCB, d_out src (packed hw-stores), ANS col-sums ----
__global__ __launch_bounds__(256) void k_gemm1(const __hip_bfloat16* __restrict__ A,
                                               const __hip_bfloat16* __restrict__ Bw,
                                               __hip_bfloat16* __restrict__ srcB,
                                               void* __restrict__ dst,
                                               float* __restrict__ ANS,
                                               const void* __restrict__ img) {
    int isbf = detect_bf(img);
    __shared__ __align__(16) __hip_bfloat16 As[128 * 32];
    __shared__ __align__(16) __hip_bfloat16 Bs[128 * 32];
    int m0 = blockIdx.x * 128, n0 = blockIdx.y * 128;
    int tid = threadIdx.x;
    int wave = tid >> 6, l = tid & 63, lm = l & 15, q = l >> 4;
    int wm = wave & 1, wn = wave >> 1;
    floatx4 zero4 = {0.f, 0.f, 0.f, 0.f};
    floatx4 acc[4][4];
    for (int i = 0; i < 4; ++i) for (int j = 0; j < 4; ++j) acc[i][j] = zero4;
    for (int k0 = 0; k0 < 512; k0 += 32) {
        __syncthreads();
        for (int s = tid; s < 512; s += 256) {
            int m = s >> 2, qq = s & 3;
            *(short8*)(As + m * 32 + qq * 8) = *(const short8*)(A + ((long)(m0 + m)) * 512 + k0 + qq * 8);
            *(short8*)(Bs + m * 32 + qq * 8) = *(const short8*)(Bw + ((long)(n0 + m)) * 512 + k0 + qq * 8);
        }
        __syncthreads();
        short8 af[4], bfv[4];
#pragma unroll
        for (int t = 0; t < 4; ++t) af[t] = *(short8*)(As + (wm * 64 + t * 16 + lm) * 32 + q * 8);
#pragma unroll
        for (int t = 0; t < 4; ++t) bfv[t] = *(short8*)(Bs + (wn * 64 + t * 16 + lm) * 32 + q * 8);
#pragma unroll
        for (int i = 0; i < 4; ++i)
#pragma unroll
            for (int j = 0; j < 4; ++j)
                acc[i][j] = __builtin_amdgcn_mfma_f32_16x16x32_bf16(af[i], bfv[j], acc[i][j], 0, 0, 0);
    }
    int b = m0 >> 10, hw0 = m0 & 1023;
    float cs[4] = {0.f, 0.f, 0.f, 0.f};
#pragma unroll
    for (int i = 0; i < 4; ++i)
#pragma unroll
        for (int j = 0; j < 4; ++j) {
            int mrow = wm * 64 + i * 16 + q * 4;
            int n = n0 + wn * 64 + j * 16 + lm;
            long mg = (long)(m0 + mrow);
#pragma unroll
            for (int r = 0; r < 4; ++r) {
                float v = acc[i][j][r];
                srcB[(mg + r) * 512 + n] = F2BF(v);
                cs[j] += v;
            }
            long obase = (long)OUT_SRC + ((long)(b * 512 + n)) * 1024 + hw0 + mrow;
            if (isbf) {
                shortx4 pk = { f2bfbits(acc[i][j][0]), f2bfbits(acc[i][j][1]),
                               f2bfbits(acc[i][j][2]), f2bfbits(acc[i][j][3]) };
                *(shortx4*)((__hip_bfloat16*)dst + obase) = pk;
            } else {
                floatx4 pk = { acc[i][j][0], acc[i][j][1], acc[i][j][2], acc[i][j][3] };
                *(floatx4*)((float*)dst + obase) = pk;
            }
        }
#pragma unroll
    for (int j = 0; j < 4; ++j) {
        cs[j] += __shfl_xor(cs[j], 16);
        cs[j] += __shfl_xor(cs[j], 32);
    }
    __syncthreads();
    float* CS = (float*)Bs;
    if (wm == 1 && q == 0) {
#pragma unroll
        for (int j = 0; j < 4; ++j) CS[wn * 64 + j * 16 + lm] = cs[j];
    }
    __syncthreads();
    if (wm == 0 && q == 0) {
#pragma unroll
        for (int j = 0; j < 4; ++j) {
            int n = n0 + wn * 64 + j * 16 + lm;
            atomicAdd(ANS + b * 512 + n, cs[j] + CS[wn * 64 + j * 16 + lm]);
        }
    }
}

// ---- ansv[b][d] = (ANS/1024)@lnW^T + lnb ; wide grid (8 b x 8 d-tiles) ----
__global__ void k_ansvec(const float* __restrict__ ANS, const void* __restrict__ lw,
                         const void* __restrict__ lb, float* __restrict__ ansv,
                         const void* __restrict__ img) {
    int isbf = detect_bf(img);
    int b = blockIdx.x, dt = blockIdx.y, tid = threadIdx.x;
    __shared__ float aL[512];
    __shared__ float R[256];
    aL[tid] = ANS[b * 512 + tid] * (1.f / 1024.f);
    aL[tid + 256] = ANS[b * 512 + tid + 256] * (1.f / 1024.f);
    __syncthreads();
    int d = dt * 64 + (tid >> 2), cl = tid & 3;
    float acc = 0.f;
    for (int k = 0; k < 128; ++k) {
        int c = cl + 4 * k;
        acc += aL[c] * inp(lw, (long)d * 512 + c, isbf);
    }
    R[tid] = acc;
    __syncthreads();
    if (cl == 0)
        ansv[b * 512 + d] = R[tid] + R[tid + 1] + R[tid + 2] + R[tid + 3] + inp(lb, d, isbf);
}

// ---- word/qa: qa=[state,ansv]; word = softmax(qa)*qa folded ----
__global__ void k_word(const float* __restrict__ ansv, const void* __restrict__ state,
                       float* __restrict__ qa, float* __restrict__ word,
                       const void* __restrict__ img) {
    int isbf = detect_bf(img);
    int b = blockIdx.x, tid = threadIdx.x;
    __shared__ float L[1024];
    __shared__ float red[256];
    L[tid] = inp(state, b * 512 + tid, isbf);
    L[tid + 256] = inp(state, b * 512 + tid + 256, isbf);
    L[tid + 512] = ansv[b * 512 + tid];
    L[tid + 768] = ansv[b * 512 + tid + 256];
    __syncthreads();
    for (int j = tid; j < 1024; j += 256) qa[b * 1024 + j] = L[j];
    float m = fmaxf(fmaxf(L[tid], L[tid + 256]), fmaxf(L[tid + 512], L[tid + 768]));
    red[tid] = m; __syncthreads();
    for (int s = 128; s > 0; s >>= 1) { if (tid < s) red[tid] = fmaxf(red[tid], red[tid + s]); __syncthreads(); }
    float M = red[0]; __syncthreads();
    float z = expf(L[tid] - M) + expf(L[tid + 256] - M) + expf(L[tid + 512] - M) + expf(L[tid + 768] - M);
    red[tid] = z; __syncthreads();
    for (int s = 128; s > 0; s >>= 1) { if (tid < s) red[tid] += red[tid + s]; __syncthreads(); }
    float Z = red[0];
    for (int j = tid; j < 512; j += 256) {
        float o1 = expf(L[j] - M) / Z * L[j];
        float o2 = expf(L[j + 512] - M) / Z * L[j + 512];
        word[b * 512 + j] = o1 + o2;
    }
}

// ---- word2[b][n] = word@txt_w^T + txt_b ----
__global__ void k_txt(const float* __restrict__ word, const void* __restrict__ tw,
                      const void* __restrict__ tb, float* __restrict__ word2,
                      const void* __restrict__ img) {
    int isbf = detect_bf(img);
    int n = blockIdx.x, tid = threadIdx.x;
    __shared__ float wL[8][512];
    __shared__ float red[256 * 8];
    for (int e = tid; e < 4096; e += 256) wL[e >> 9][e & 511] = word[e];
    __syncthreads();
    float acc[8] = {0, 0, 0, 0, 0, 0, 0, 0};
    for (int c = tid; c < 512; c += 256) {
        float tv = inp(tw, (long)n * 512 + c, isbf);
        for (int b = 0; b < 8; ++b) acc[b] += wL[b][c] * tv;
    }
    for (int b = 0; b < 8; ++b) red[tid * 8 + b] = acc[b];
    __syncthreads();
    for (int s = 128; s > 0; s >>= 1) {
        if (tid < s) for (int b = 0; b < 8; ++b) red[tid * 8 + b] += red[(tid + s) * 8 + b];
        __syncthreads();
    }
    if (tid < 8) word2[tid * 2305 + n] = red[tid] + inp(tb, n, isbf);
}

// ---- eff_w / eff_b ----
__global__ void k_eff(const float* __restrict__ word2, const void* __restrict__ w3,
                      const void* __restrict__ b3, float* __restrict__ effw,
                      float* __restrict__ effb, const void* __restrict__ img) {
    int isbf = detect_bf(img);
    int bid = blockIdx.x;
    int b = bid / 9, tap = bid - b * 9;
    int tid = threadIdx.x;
    __shared__ float dw[256];
    dw[tid] = word2[b * 2305 + tid * 9 + tap];
    __syncthreads();
    float acc = 0.f;
    for (int c = 0; c < 256; ++c) acc += dw[c] * inp(w3, c * 256 + tid, isbf);
    effw[(b * 9 + tap) * 256 + tid] = acc;
    if (tid == 0) {
        float e = 0.f;
        for (int c = 0; c < 256; ++c) e += dw[c] * inp(b3, c, isbf);
        effb[b * 9 + tap] = e;
    }
}

// ---- conv: 8x8 px tile, acc[2][4] (32 AGPR), coalesced B, 3 waves/SIMD target ----
// 3x3 pad1 on 2x-bilinear-upsampled NHWC bf16 input, Cin=512, bf16 MFMA.
// wRt layout: [tap][cc][co][32ci] -> wave B-frag load = one contiguous 1KB.
__global__ __launch_bounds__(256, 3) void k_conv(const __hip_bfloat16* __restrict__ in,
                                                 const __hip_bfloat16* __restrict__ wRt,
                                                 __hip_bfloat16* __restrict__ out,
                                                 int inH, int inW, int Cout,
                                                 float* __restrict__ s1o, float* __restrict__ s2o,
                                                 const float* __restrict__ bnS1,
                                                 const float* __restrict__ bnS2,
                                                 const void* __restrict__ g,
                                                 const void* __restrict__ bb, float invN,
                                                 const void* __restrict__ img) {
    int OH = inH * 2, OW = inW * 2;
    int tXn = OW >> 3, tYn = OH >> 3;
    int bid = blockIdx.x;
    int tX = bid % tXn; int tmp = bid / tXn; int tY = tmp % tYn; int b = tmp / tYn;
    int co0 = blockIdx.y * 128;
    __shared__ __align__(16) __hip_bfloat16 Os[36 * 32];    // orig tile 6y x 6x
    __shared__ __align__(16) __hip_bfloat16 Ah[100 * 32];   // up halo 10y x 10x
    __shared__ float scT[512];
    __shared__ float shT[512];
    int tid = threadIdx.x;
    int wave = tid >> 6, l = tid & 63, lm = l & 15, q = l >> 4;
    int wm = wave & 1, wn = wave >> 1;
    int dobn = (bnS1 != nullptr);
    if (dobn) {
        int isbf = detect_bf(img);
        for (int c = tid; c < 512; c += 256) {
            float m = bnS1[c] * invN, var = bnS2[c] * invN - m * m;
            float sc = inp(g, c, isbf) * rsqrtf(var + 1e-5f);
            scT[c] = sc; shT[c] = inp(bb, c, isbf) - m * sc;
        }
    }
    int R0m1 = (tY << 2) - 1;
    int C0m1 = (tX << 2) - 1;
    floatx4 zero4 = {0.f, 0.f, 0.f, 0.f};
    floatx4 acc[2][4];
    for (int i = 0; i < 2; ++i) for (int j = 0; j < 4; ++j) acc[i][j] = zero4;

    for (int ci0 = 0; ci0 < 512; ci0 += 32) {
        __syncthreads();
        // stage orig-res tile (clamped): 36 px x 32 ci
        if (tid < 144) {
            int p = tid >> 2, sub = tid & 3;
            int r = p / 6, cx = p - r * 6;
            int gr = R0m1 + r; gr = gr < 0 ? 0 : (gr > inH - 1 ? inH - 1 : gr);
            int gc = C0m1 + cx; gc = gc < 0 ? 0 : (gc > inW - 1 ? inW - 1 : gc);
            short8 raw = *(const short8*)(in + ((long)(b * inH + gr) * inW + gc) * 512 + ci0 + sub * 8);
            if (dobn) {
#pragma unroll
                for (int k = 0; k < 8; ++k) {
                    int c = ci0 + sub * 8 + k;
                    float v = bfbits2f(raw[k]) * scT[c] + shT[c];
                    raw[k] = f2bfbits(v > 0.f ? v : 0.f);
                }
            }
            *(short8*)(Os + p * 32 + sub * 8) = raw;
        }
        __syncthreads();
        // build upsampled halo from LDS: 100 px x 4 octets (round-3-validated lerp)
        for (int e = tid; e < 400; e += 256) {
            int p = e >> 2, sub = e & 3;
            int hy = p / 10, hx = p - hy * 10;
            int gy = (tY << 3) + hy - 1, gx = (tX << 3) + hx - 1;
            short8 res = {0, 0, 0, 0, 0, 0, 0, 0};
            if (gy >= 0 && gy < OH && gx >= 0 && gx < OW) {
                int r0; float wy0;
                if (gy & 1) { r0 = gy >> 1; wy0 = 0.75f; } else { r0 = (gy >> 1) - 1; wy0 = 0.25f; }
                int r1 = r0 + 1;
                if (r0 < 0) r0 = 0; if (r1 > inH - 1) r1 = inH - 1;
                int s0; float wx0;
                if (gx & 1) { s0 = gx >> 1; wx0 = 0.75f; } else { s0 = (gx >> 1) - 1; wx0 = 0.25f; }
                int s1 = s0 + 1;
                if (s0 < 0) s0 = 0; if (s1 > inW - 1) s1 = inW - 1;
                int lr0 = r0 - R0m1, lr1 = r1 - R0m1;
                int lc0 = s0 - C0m1, lc1 = s1 - C0m1;
                float wy1 = 1.f - wy0, wx1 = 1.f - wx0;
                float w00 = wy0 * wx0, w01 = wy0 * wx1, w10 = wy1 * wx0, w11 = wy1 * wx1;
                short8 v00 = *(const short8*)(Os + (lr0 * 6 + lc0) * 32 + sub * 8);
                short8 v01 = *(const short8*)(Os + (lr0 * 6 + lc1) * 32 + sub * 8);
                short8 v10 = *(const short8*)(Os + (lr1 * 6 + lc0) * 32 + sub * 8);
                short8 v11 = *(const short8*)(Os + (lr1 * 6 + lc1) * 32 + sub * 8);
#pragma unroll
                for (int k = 0; k < 8; ++k) {
                    float f = w00 * bfbits2f(v00[k]) + w01 * bfbits2f(v01[k]) +
                              w10 * bfbits2f(v10[k]) + w11 * bfbits2f(v11[k]);
                    res[k] = f2bfbits(f);
                }
            }
            *(short8*)(Ah + p * 32 + sub * 8) = res;
        }
        __syncthreads();
        int cc = ci0 >> 5;
#pragma unroll
        for (int tap = 0; tap < 9; ++tap) {
            int ky = tap / 3, kx = tap - ky * 3;
            short8 bfv[4];
#pragma unroll
            for (int j = 0; j < 4; ++j)
                bfv[j] = *(const short8*)(wRt + ((long)(tap * 16 + cc) * Cout + co0 + wn * 64 + j * 16 + lm) * 32 + q * 8);
            short8 af[2];
#pragma unroll
            for (int i = 0; i < 2; ++i) {
                int px = wm * 32 + i * 16 + lm;
                af[i] = *(short8*)(Ah + (((px >> 3) + ky) * 10 + (px & 7) + kx) * 32 + q * 8);
            }
#pragma unroll
            for (int i = 0; i < 2; ++i)
#pragma unroll
                for (int j = 0; j < 4; ++j)
                    acc[i][j] = __builtin_amdgcn_mfma_f32_16x16x32_bf16(af[i], bfv[j], acc[i][j], 0, 0, 0);
        }
    }
    // epilogue: stores + per-channel stats
    float s1v[4] = {0.f, 0.f, 0.f, 0.f}, s2v[4] = {0.f, 0.f, 0.f, 0.f};
#pragma unroll
    for (int i = 0; i < 2; ++i) {
#pragma unroll
        for (int j = 0; j < 4; ++j) {
            int cob = co0 + wn * 64 + j * 16 + lm;
#pragma unroll
            for (int r = 0; r < 4; ++r) {
                int px = wm * 32 + i * 16 + q * 4 + r;
                int oy = (tY << 3) + (px >> 3), ox = (tX << 3) + (px & 7);
                float v = acc[i][j][r];
                out[(((long)(b * OH + oy)) * OW + ox) * Cout + cob] = F2BF(v);
                s1v[j] += v; s2v[j] += v * v;
            }
        }
    }
#pragma unroll
    for (int j = 0; j < 4; ++j) {
        s1v[j] += __shfl_xor(s1v[j], 16); s1v[j] += __shfl_xor(s1v[j], 32);
        s2v[j] += __shfl_xor(s2v[j], 16); s2v[j] += __shfl_xor(s2v[j], 32);
    }
    __syncthreads();
    float* RB = (float*)Ah;
    if (wm == 1 && q == 0) {
#pragma unroll
        for (int j = 0; j < 4; ++j) {
            int idx = wn * 64 + j * 16 + lm;
            RB[idx] = s1v[j]; RB[128 + idx] = s2v[j];
        }
    }
    __syncthreads();
    if (wm == 0 && q == 0) {
#pragma unroll
        for (int j = 0; j < 4; ++j) {
            int idx = wn * 64 + j * 16 + lm;
            atomicAdd(s1o + co0 + idx, s1v[j] + RB[idx]);
            atomicAdd(s2o + co0 + idx, s2v[j] + RB[128 + idx]);
        }
    }
}

// ---- masks: inline bn2+relu (vectorized staging), fused (conv3 ∘ dyn conv) ----
__global__ __launch_bounds__(256) void k_masks(const __hip_bfloat16* __restrict__ x2,
                                               const float* __restrict__ effw,
                                               const float* __restrict__ effb,
                                               const float* __restrict__ word2,
                                               void* __restrict__ mout,
                                               const float* __restrict__ s1,
                                               const float* __restrict__ s2,
                                               const void* __restrict__ g,
                                               const void* __restrict__ bb, float invN,
                                               const void* __restrict__ img) {
    int isbf = detect_bf(img);
    int bid = blockIdx.x;
    int tX = bid & 15, tY = (bid >> 4) & 15, b = bid >> 8;
    __shared__ __align__(16) __hip_bfloat16 H[100 * 264];
    __shared__ __align__(16) float EW[9 * 256];
    __shared__ float EB[9];
    __shared__ float sc2T[256];
    __shared__ float sh2T[256];
    int tid = threadIdx.x;
    {
        float m = s1[tid] * invN, var = s2[tid] * invN - m * m;
        float sc = inp(g, tid, isbf) * rsqrtf(var + 1e-5f);
        sc2T[tid] = sc; sh2T[tid] = inp(bb, tid, isbf) - m * sc;
    }
    __syncthreads();
    for (int e = tid; e < 3200; e += 256) {
        int c8 = e & 31, p = e >> 5;
        int hy = p / 10, hx = p - hy * 10;
        int gy = tY * 8 + hy - 1, gx = tX * 8 + hx - 1;
        short8 res = {0, 0, 0, 0, 0, 0, 0, 0};
        if (gy >= 0 && gy < 128 && gx >= 0 && gx < 128) {
            short8 raw = *(const short8*)(x2 + (((long)(b * 128 + gy)) * 128 + gx) * 256 + c8 * 8);
#pragma unroll
            for (int k = 0; k < 8; ++k) {
                int c = c8 * 8 + k;
                float v = bfbits2f(raw[k]) * sc2T[c] + sh2T[c];
                res[k] = f2bfbits(v > 0.f ? v : 0.f);
            }
        }
        *(short8*)(H + p * 264 + c8 * 8) = res;
    }
    for (int e = tid; e < 2304; e += 256) EW[e] = effw[b * 2304 + e];
    if (tid < 9) EB[tid] = effb[b * 9 + tid];
    __syncthreads();
    int px = tid & 63, part = tid >> 6;
    int py = px >> 3, pxc = px & 7;
    int cbase = part * 64;
    float acc = 0.f;
    for (int tap = 0; tap < 9; ++tap) {
        int ky = tap / 3, kx = tap - ky * 3;
        int hp = (py + ky) * 10 + pxc + kx;
        const __hip_bfloat16* hrow = H + (long)hp * 264 + cbase;
        const float* erow = EW + tap * 256 + cbase;
#pragma unroll
        for (int c8 = 0; c8 < 8; ++c8) {
            short8 h8 = *(const short8*)(hrow + c8 * 8);
            floatx4 e0 = *(const floatx4*)(erow + c8 * 8);
            floatx4 e1 = *(const floatx4*)(erow + c8 * 8 + 4);
            acc += bfbits2f(h8[0]) * e0[0] + bfbits2f(h8[1]) * e0[1] +
                   bfbits2f(h8[2]) * e0[2] + bfbits2f(h8[3]) * e0[3] +
                   bfbits2f(h8[4]) * e1[0] + bfbits2f(h8[5]) * e1[1] +
                   bfbits2f(h8[6]) * e1[2] + bfbits2f(h8[7]) * e1[3];
        }
    }
    float (*red)[64] = (float(*)[64])sc2T;   // dead after staging
    red[part][px] = acc;
    __syncthreads();
    if (part == 0) {
        float s = red[0][px] + red[1][px] + red[2][px] + red[3][px];
        int oy = tY * 8 + py, ox = tX * 8 + pxc;
        float bias = word2[b * 2305 + 2304];
        for (int tap = 0; tap < 9; ++tap) {
            int ky = tap / 3, kx = tap - ky * 3;
            int iy = oy + ky - 1, ix = ox + kx - 1;
            if (iy >= 0 && iy < 128 && ix >= 0 && ix < 128) bias += EB[tap];
        }
        outw(mout, b * 16384 + oy * 128 + ox, s + bias, isbf);
    }
}

// ---- hid[b][h] = relu(qa@w1^T + b1) ; wide grid (8 b x 4 h-tiles) ----
__global__ void k_hid(const float* __restrict__ qa, const void* __restrict__ w1,
                      const void* __restrict__ b1, float* __restrict__ hid,
                      const void* __restrict__ img) {
    int isbf = detect_bf(img);
    int b = blockIdx.x, ht = blockIdx.y, tid = threadIdx.x;
    __shared__ float qL[1024];
    __shared__ float R[256];
    for (int j = tid; j < 1024; j += 256) qL[j] = qa[b * 1024 + j];
    __syncthreads();
    int h = ht * 64 + (tid >> 2), cl = tid & 3;
    float acc = 0.f;
    for (int k = 0; k < 256; ++k) {
        int c = cl + 4 * k;
        acc += qL[c] * inp(w1, (long)h * 1024 + c, isbf);
    }
    R[tid] = acc;
    __syncthreads();
    if (cl == 0) {
        float v = R[tid] + R[tid + 1] + R[tid + 2] + R[tid + 3] + inp(b1, h, isbf);
        hid[b * 256 + h] = v > 0.f ? v : 0.f;
    }
}

// ---- logits: gates softmax + feat + experts ----
__global__ void k_logits(const float* __restrict__ hid, const float* __restrict__ ansv,
                         const void* __restrict__ w2, const void* __restrict__ b2,
                         const void* __restrict__ lw2, const void* __restrict__ lb2,
                         const void* __restrict__ ew, const void* __restrict__ ebias,
                         void* __restrict__ out, const void* __restrict__ img) {
    int isbf = detect_bf(img);
    int b = blockIdx.x, tid = threadIdx.x;
    __shared__ float hidL[256], avL[512], gates[8], feat[128], R[256];
    hidL[tid] = hid[b * 256 + tid];
    for (int j = tid; j < 512; j += 256) avL[j] = ansv[b * 512 + j];
    __syncthreads();
    if (tid < 8) {
        float gl = inp(b2, tid, isbf);
        for (int j = 0; j < 256; ++j) gl += hidL[j] * inp(w2, tid * 256 + j, isbf);
        gates[tid] = gl;
    }
    // feat partials: 2 threads per f
    int f = tid >> 1, half = tid & 1;
    float acc = 0.f;
    for (int k = 0; k < 256; ++k) {
        int c = half + 2 * k;
        acc += avL[c] * inp(lw2, (long)f * 512 + c, isbf);
    }
    R[tid] = acc;
    __syncthreads();
    if (tid == 0) {
        float mx = gates[0];
        for (int e = 1; e < 8; ++e) mx = fmaxf(mx, gates[e]);
        float z = 0.f;
        for (int e = 0; e < 8; ++e) { gates[e] = expf(gates[e] - mx); z += gates[e]; }
        for (int e = 0; e < 8; ++e) gates[e] /= z;
    }
    if (half == 0) feat[f] = R[tid] + R[tid + 1] + inp(lb2, f, isbf);
    __syncthreads();
    if (tid < 23) {
        float a = 0.f;
        for (int e = 0; e < 8; ++e) {
            float d = inp(ebias, e * 23 + tid, isbf);
            for (int ff = 0; ff < 128; ++ff) d += inp(ew, (e * 23 + tid) * 128 + ff, isbf) * feat[ff];
            a += gates[e] * d;
        }
        outw(out, OUT_LOGITS + b * 23 + tid, a, isbf);
    }
}

extern "C" void kernel_launch(void* const* d_in, const int* in_sizes, int n_in,
                              void* d_out, int out_size, void* d_ws, size_t ws_size,
                              hipStream_t stream) {
    (void)in_sizes; (void)n_in; (void)out_size; (void)ws_size;
    const void* img   = d_in[0];
    const void* state = d_in[2];
    const void* Wt    = d_in[4];
    const void* cw1   = d_in[7];
    const void* g1    = d_in[8];
    const void* bb1   = d_in[9];
    const void* cw2   = d_in[10];
    const void* g2    = d_in[11];
    const void* bb2   = d_in[12];
    const void* w3    = d_in[13];
    const void* b3    = d_in[14];
    const void* txtw  = d_in[15];
    const void* txtb  = d_in[16];
    const void* lnw   = d_in[17];
    const void* lnb   = d_in[18];
    const void* lnw2  = d_in[19];
    const void* lnb2  = d_in[20];
    const void* rw1   = d_in[21];
    const void* rb1   = d_in[22];
    const void* rw2   = d_in[23];
    const void* rb2   = d_in[24];
    const void* ew    = d_in[25];
    const void* eb    = d_in[26];

    char* ws = (char*)d_ws;
    __hip_bfloat16* A    = (__hip_bfloat16*)(ws + WS_A);
    __hip_bfloat16* WTB  = (__hip_bfloat16*)(ws + WS_WTB);
    __hip_bfloat16* WR1  = (__hip_bfloat16*)(ws + WS_WR1);
    __hip_bfloat16* WR2  = (__hip_bfloat16*)(ws + WS_WR2);
    __hip_bfloat16* SRCB = (__hip_bfloat16*)(ws + WS_SRCB);
    __hip_bfloat16* Y1   = (__hip_bfloat16*)(ws + WS_Y1);
    __hip_bfloat16* Y2   = (__hip_bfloat16*)(ws + WS_Y2);
    float* S1A = (float*)(ws + WS_STATS);
    float* S2A = S1A + 512;
    float* S1B = S1A + 1024;
    float* S2B = S1A + 1536;
    float* ANS   = (float*)(ws + WS_ANS);
    float* QA    = (float*)(ws + WS_QA);
    float* ANSV  = (float*)(ws + WS_ANSV);
    float* WORD  = (float*)(ws + WS_WORD);
    float* WORD2 = (float*)(ws + WS_WORD2);
    float* EFFW  = (float*)(ws + WS_EFFW);
    float* EFFB  = (float*)(ws + WS_EFFB);
    float* HID   = (float*)(ws + WS_HID);

    hipMemsetAsync(ws + WS_STATS, 0, 24576, stream);

    k_pre<<<5888, 256, 0, stream>>>(img, cw1, cw2, Wt, A, WR1, WR2, WTB);
    k_gemm1<<<dim3(64, 4), 256, 0, stream>>>(A, WTB, SRCB, d_out, ANS, img);
    k_ansvec<<<dim3(8, 8), 256, 0, stream>>>(ANS, lnw, lnb, ANSV, img);
    k_word<<<8, 256, 0, stream>>>(ANSV, state, QA, WORD, img);
    k_txt<<<2305, 256, 0, stream>>>(WORD, txtw, txtb, WORD2, img);
    k_eff<<<72, 256, 0, stream>>>(WORD2, w3, b3, EFFW, EFFB, img);
    // conv1: src -up2x-> 64x64 -> 3x3 -> Y1 raw ; stats -> S1A/S2A
    k_conv<<<dim3(512, 4), 256, 0, stream>>>(SRCB, WR1, Y1, 32, 32, 512, S1A, S2A,
                                             nullptr, nullptr, nullptr, nullptr, 0.f, img);
    // conv2: bn1(Y1)+relu inline -up2x-> 128x128 -> 3x3 -> Y2 raw ; stats -> S1B/S2B
    k_conv<<<dim3(2048, 2), 256, 0, stream>>>(Y1, WR2, Y2, 64, 64, 256, S1B, S2B,
                                              S1A, S2A, g1, bb1, 1.f / 32768.f, img);
    k_masks<<<2048, 256, 0, stream>>>(Y2, EFFW, EFFB, WORD2, d_out,
                                      S1B, S2B, g2, bb2, 1.f / 131072.f, img);
    k_hid<<<dim3(8, 4), 256, 0, stream>>>(QA, rw1, rb1, HID, img);
    k_logits<<<8, 256, 0, stream>>>(HID, ANSV, rw2, rb2, lnw2, lnb2, ew, eb, d_out, img);
}